// Round 10
// baseline (347.364 us; speedup 1.0000x reference)
//
#include <hip/hip_runtime.h>
#include <hip/hip_bf16.h>

#define NG 100000
#define NU 100000
#define NE 3200000
#define NC 2000000

// dst-bucket binning: 128 dsts per bucket
#define BSZ 128
#define NBK 782          // ceil(NG/BSZ)
#define NBKP 800         // padded array size
#define CAP 5120         // entries per bucket (mean 4096, +16 sigma)
#define CHUNK 4096       // edges per k_bin block (38KB LDS -> 4 blocks/CU)

typedef __attribute__((ext_vector_type(8))) short short8;
typedef __attribute__((ext_vector_type(4))) float floatx4;
typedef unsigned short ushortx8 __attribute__((ext_vector_type(8)));

// branchless SELU on the HW transcendental (6 VALU ops)
__device__ __forceinline__ float selu_f(float x) {
    const float LAM = 1.0507009873554805f;
    const float ALA = 1.7580993408473766f;  // LAM * ALPHA
    const float L2E = 1.44269504088896340736f;
    float e = __builtin_amdgcn_exp2f(fminf(x, 0.f) * L2E);
    return fmaf(LAM, fmaxf(x, 0.f), fmaf(ALA, e, -ALA));
}

__device__ __forceinline__ float bfbits2f(unsigned short u) {
    return __uint_as_float(((unsigned)u) << 16);
}

__device__ __forceinline__ unsigned short f2bfbits(float f) {
    union { __hip_bfloat16 h; unsigned short u; } cv;
    cv.h = __float2bfloat16(f);
    return cv.u;
}

__device__ __forceinline__ float ldf(const void* p, int i, int isbf) {
    return isbf ? bfbits2f(((const unsigned short*)p)[i]) : ((const float*)p)[i];
}

// ---- dtype detection: flags[0]=floats-are-bf16, flags[1]=cand-is-i64,
//      flags[2]=edges-is-i64 ------------------------------------------------
__global__ void k_detect(const unsigned int* __restrict__ xw,
                         const unsigned int* __restrict__ cw,
                         const unsigned int* __restrict__ ew,
                         int* __restrict__ flags) {
    if (threadIdx.x != 0 || blockIdx.x != 0) return;
    int nb = 0;
    for (int i = 0; i < 64; ++i) {
        unsigned lo = xw[i] & 0xffffu;
        unsigned e = (lo >> 7) & 0xff;
        if (e >= 112 && e <= 134) ++nb;
    }
    flags[0] = (nb >= 32) ? 1 : 0;
    int cz = 0, ez = 0;
    for (int i = 0; i < 64; ++i) {
        if (cw[2 * i + 1] == 0u) ++cz;
        if (ew[2 * i + 1] == 0u) ++ez;
    }
    flags[1] = (cz >= 48) ? 1 : 0;
    flags[2] = (ez >= 48) ? 1 : 0;
}

__device__ __forceinline__ void ld_edge(const void* edges, long long e, int e64,
                                        int& s, int& d) {
    if (e64) {
        const long long* el = (const long long*)edges;
        s = (int)el[e];
        d = (int)el[NE + e];
    } else {
        const int* ei = (const int*)edges;
        s = ei[e];
        d = ei[NE + e];
    }
}

// ---- Bucket-sorted edge build with COALESCED writes -----------------------
__global__ __launch_bounds__(256) void k_bin(const void* __restrict__ edges,
        int* __restrict__ gcur, unsigned int* __restrict__ glist,
        const int* __restrict__ flags) {
    __shared__ unsigned int ord[CHUNK];        // 16 KB
    __shared__ unsigned short ordb[CHUNK];     // 8 KB
    __shared__ int hist[NBKP];
    __shared__ int lstart[NBKP];
    __shared__ int ofs[NBKP];
    __shared__ int gbase[NBKP];
    __shared__ int psum[256];                  // total ~38 KB -> 4 blocks/CU

    int tid = threadIdx.x;
    long long base = (long long)blockIdx.x * CHUNK;
    int chunk = (int)(NE - base);
    if (chunk > CHUNK) chunk = CHUNK;
    int e64 = flags[2];

    for (int b = tid; b < NBKP; b += 256) hist[b] = 0;
    __syncthreads();

    // phase A: histogram
    for (int i = 0; i < CHUNK / 256; ++i) {
        int idx = i * 256 + tid;
        if (idx < chunk) {
            int s, d;
            ld_edge(edges, base + idx, e64, s, d);
            atomicAdd(&hist[d >> 7], 1);
        }
    }
    __syncthreads();

    // phase B: exclusive scan + global range reservation
    int bb = tid * 4;
    int h0 = (bb + 0 < NBKP) ? hist[bb + 0] : 0;
    int h1 = (bb + 1 < NBKP) ? hist[bb + 1] : 0;
    int h2 = (bb + 2 < NBKP) ? hist[bb + 2] : 0;
    int h3 = (bb + 3 < NBKP) ? hist[bb + 3] : 0;
    int tsum = h0 + h1 + h2 + h3;
    psum[tid] = tsum;
    __syncthreads();
    for (int off = 1; off < 256; off <<= 1) {
        int v = (tid >= off) ? psum[tid - off] : 0;
        __syncthreads();
        psum[tid] += v;
        __syncthreads();
    }
    int excl = psum[tid] - tsum;
    if (bb + 0 < NBKP) { lstart[bb + 0] = excl; }
    if (bb + 1 < NBKP) { lstart[bb + 1] = excl + h0; }
    if (bb + 2 < NBKP) { lstart[bb + 2] = excl + h0 + h1; }
    if (bb + 3 < NBKP) { lstart[bb + 3] = excl + h0 + h1 + h2; }
    for (int k = 0; k < 4; ++k) {
        int b = bb + k;
        if (b < NBKP) {
            int c = hist[b];
            int g = 0;
            if (c > 0 && b < NBK) g = atomicAdd(&gcur[b], c);
            gbase[b] = g;
            ofs[b] = lstart[b];
        }
    }
    __syncthreads();

    // phase C: reorder by bucket into LDS
    for (int i = 0; i < CHUNK / 256; ++i) {
        int idx = i * 256 + tid;
        if (idx < chunk) {
            int s, d;
            ld_edge(edges, base + idx, e64, s, d);
            int b = d >> 7;
            int pos = atomicAdd(&ofs[b], 1);
            ord[pos] = ((unsigned)s << 7) | (unsigned)(d & 127);
            ordb[pos] = (unsigned short)b;
        }
    }
    __syncthreads();

    // phase D: coalesced write-out
    for (int i = 0; i < CHUNK / 256; ++i) {
        int idx = i * 256 + tid;
        if (idx < chunk) {
            int b = ordb[idx];
            int p = gbase[b] + (idx - lstart[b]);
            if (p < CAP) glist[(long long)b * CAP + p] = ord[idx];
        }
    }
}

// ---- Counting-sort each bucket by dl, in place; emit per-dst CSR ----------
__global__ __launch_bounds__(256) void k_sort(const int* __restrict__ gcur,
        unsigned int* __restrict__ glist,
        int* __restrict__ dstoff, int* __restrict__ ddeg) {
    __shared__ unsigned int sorted[CAP];   // 20 KB
    __shared__ int hist[BSZ];
    __shared__ int incl[BSZ];
    __shared__ int cur[BSZ];
    int b = blockIdx.x;
    int tid = threadIdx.x;
    int cnt = gcur[b];
    if (cnt > CAP) cnt = CAP;
    unsigned int* lp = glist + (long long)b * CAP;

    if (tid < BSZ) hist[tid] = 0;
    __syncthreads();
    for (int k = tid; k < cnt; k += 256)
        atomicAdd(&hist[lp[k] & 127], 1);
    __syncthreads();
    if (tid < BSZ) incl[tid] = hist[tid];
    __syncthreads();
    for (int off = 1; off < BSZ; off <<= 1) {
        int v = (tid < BSZ && tid >= off) ? incl[tid - off] : 0;
        __syncthreads();
        if (tid < BSZ && tid >= off) incl[tid] += v;
        __syncthreads();
    }
    if (tid < BSZ) {
        int excl = incl[tid] - hist[tid];
        cur[tid] = excl;
        int d = b * BSZ + tid;
        if (d < NG) {
            dstoff[d] = b * CAP + excl;
            ddeg[d] = hist[tid];
        }
    }
    __syncthreads();
    for (int k = tid; k < cnt; k += 256) {
        unsigned u = lp[k];
        int pos = atomicAdd(&cur[u & 127], 1);
        sorted[pos] = u >> 7;
    }
    __syncthreads();
    for (int k = tid; k < cnt; k += 256) lp[k] = sorted[k];
}

// ---- Gather 1: 8 threads/dst, slim (high occupancy), partials to pagg1 ----
__global__ __launch_bounds__(256) void k_gather1(const int* __restrict__ dstoff,
        const int* __restrict__ ddeg, const unsigned int* __restrict__ glist,
        const void* __restrict__ xg, float4* __restrict__ pagg1,
        const int* __restrict__ flags) {
    int gid = blockIdx.x * 256 + threadIdx.x;
    int d = gid >> 3;
    if (d >= NG) return;
    int q = gid & 7;
    int isbf = flags[0];
    int start = dstoff[d];
    int deg = ddeg[d];
    float a0 = 0.f, a1 = 0.f, a2 = 0.f, a3 = 0.f;
    for (int k = q; k < deg; k += 8) {
        int s = glist[start + k];
        if (isbf) {
            ushort4 r = *(const ushort4*)((const unsigned short*)xg + s * 4);
            a0 += bfbits2f(r.x); a1 += bfbits2f(r.y);
            a2 += bfbits2f(r.z); a3 += bfbits2f(r.w);
        } else {
            float4 r = *(const float4*)((const float*)xg + s * 4);
            a0 += r.x; a1 += r.y; a2 += r.z; a3 += r.w;
        }
    }
#pragma unroll
    for (int off = 1; off < 8; off <<= 1) {
        a0 += __shfl_xor(a0, off);
        a1 += __shfl_xor(a1, off);
        a2 += __shfl_xor(a2, off);
        a3 += __shfl_xor(a3, off);
    }
    if (q == 0) pagg1[d] = make_float4(a0, a1, a2, a3);
}

// ---- Node 1: MLP -> hbf (bf16) --------------------------------------------
__global__ __launch_bounds__(256) void k_node1(const float4* __restrict__ pagg1,
        const void* __restrict__ xg,
        const void* __restrict__ W1r, const void* __restrict__ W1o,
        const void* __restrict__ b1, ushortx8* __restrict__ hbf,
        const int* __restrict__ flags) {
    int d = blockIdx.x * 256 + threadIdx.x;
    if (d >= NG) return;
    int isbf = flags[0];
    float4 av = pagg1[d];
    float a[4] = {av.x, av.y, av.z, av.w};
    float x[4];
#pragma unroll
    for (int c = 0; c < 4; ++c) x[c] = ldf(xg, d * 4 + c, isbf);
    ushortx8 o;
#pragma unroll
    for (int j = 0; j < 8; ++j) {
        float v = ldf(b1, j, isbf);
#pragma unroll
        for (int c = 0; c < 4; ++c)
            v += a[c] * ldf(W1r, c * 8 + j, isbf)
               + x[c] * ldf(W1o, c * 8 + j, isbf);
        o[j] = f2bfbits(selu_f(v));
    }
    hbf[d] = o;
}

// ---- Gather 2: 8 threads/dst, slim, partials to pagg2 ---------------------
__global__ __launch_bounds__(256) void k_gather2(const int* __restrict__ dstoff,
        const int* __restrict__ ddeg, const unsigned int* __restrict__ glist,
        const ushortx8* __restrict__ hbf, float4* __restrict__ pagg2,
        const int* __restrict__ flags) {
    int gid = blockIdx.x * 256 + threadIdx.x;
    int d = gid >> 3;
    if (d >= NG) return;
    int q = gid & 7;
    int start = dstoff[d];
    int deg = ddeg[d];
    float a[8] = {0.f, 0.f, 0.f, 0.f, 0.f, 0.f, 0.f, 0.f};
    for (int k = q; k < deg; k += 8) {
        int s = glist[start + k];
        ushortx8 r = hbf[s];
#pragma unroll
        for (int c = 0; c < 8; ++c) a[c] += bfbits2f((unsigned short)r[c]);
    }
#pragma unroll
    for (int off = 1; off < 8; off <<= 1) {
#pragma unroll
        for (int c = 0; c < 8; ++c) a[c] += __shfl_xor(a[c], off);
    }
    if (q == 0) {
        pagg2[2 * d + 0] = make_float4(a[0], a[1], a[2], a[3]);
        pagg2[2 * d + 1] = make_float4(a[4], a[5], a[6], a[7]);
    }
}

// ---- Node 2: MLP -> xs (bf16) ---------------------------------------------
__global__ __launch_bounds__(256) void k_node2(const float4* __restrict__ pagg2,
        const ushortx8* __restrict__ hbf,
        const void* __restrict__ W2r, const void* __restrict__ W2o,
        const void* __restrict__ b2, unsigned short* __restrict__ xs,
        const int* __restrict__ flags) {
    int d = blockIdx.x * 256 + threadIdx.x;
    if (d >= NG) return;
    int isbf = flags[0];
    float4 p0 = pagg2[2 * d + 0];
    float4 p1 = pagg2[2 * d + 1];
    float a[8] = {p0.x, p0.y, p0.z, p0.w, p1.x, p1.y, p1.z, p1.w};
    ushortx8 hr = hbf[d];
    float hv[8];
#pragma unroll
    for (int c = 0; c < 8; ++c) hv[c] = bfbits2f((unsigned short)hr[c]);
    ushortx8 lo, hi;
#pragma unroll
    for (int j = 0; j < 16; ++j) {
        float v = ldf(b2, j, isbf);
#pragma unroll
        for (int c = 0; c < 8; ++c)
            v += a[c] * ldf(W2r, c * 16 + j, isbf)
               + hv[c] * ldf(W2o, c * 16 + j, isbf);
        unsigned short bb16 = f2bfbits(selu_f(v));
        if (j < 8) lo[j] = bb16; else hi[j - 8] = bb16;
    }
    ushortx8* xp = (ushortx8*)(xs + d * 16);
    xp[0] = lo;
    xp[1] = hi;
}

// ---- fc_unconnected -> x_stacked[NG:NG+NU] (bf16), NO selu ----------------
__global__ __launch_bounds__(256) void k_unconn(const void* __restrict__ xu,
        const void* __restrict__ Wun, const void* __restrict__ bun,
        unsigned short* __restrict__ xs, const int* __restrict__ flags) {
    int u = blockIdx.x * 256 + threadIdx.x;
    if (u >= NU) return;
    int isbf = flags[0];
    float x[4];
#pragma unroll
    for (int k = 0; k < 4; ++k) x[k] = ldf(xu, u * 4 + k, isbf);
    ushortx8 lo, hi;
#pragma unroll
    for (int j = 0; j < 16; ++j) {
        float v = ldf(bun, j, isbf);
#pragma unroll
        for (int k = 0; k < 4; ++k)
            v += x[k] * ldf(Wun, k * 16 + j, isbf);
        unsigned short bb = f2bfbits(v);
        if (j < 8) lo[j] = bb; else hi[j - 8] = bb;
    }
    ushortx8* xp = (ushortx8*)(xs + (NG + u) * 16);
    xp[0] = lo;
    xp[1] = hi;
}

// ---- FC head: persistent waves, 2 tiles/iter, MFMA 16x16x32 bf16 ----------
__global__ __launch_bounds__(256) void k_fc(const unsigned short* __restrict__ xs,
        const void* __restrict__ cand,
        const void* __restrict__ Wfc1, const void* __restrict__ bfc1,
        const void* __restrict__ Wfc2, const void* __restrict__ bfc2,
        void* __restrict__ out, const int* __restrict__ flags) {
    int lane = threadIdx.x & 63;
    int wid = (blockIdx.x * blockDim.x + threadIdx.x) >> 6;
    int m = lane & 15;
    int half = lane >> 4;
    int isbf = flags[0], c64 = flags[1];

    short8 bfrag[4];
#pragma unroll
    for (int t = 0; t < 4; ++t) {
#pragma unroll
        for (int j = 0; j < 8; ++j)
            bfrag[t][j] = (short)f2bfbits(ldf(Wfc1, (half * 8 + j) * 64 + t * 16 + m, isbf));
    }
    float bias[4], w2v[4];
#pragma unroll
    for (int t = 0; t < 4; ++t) {
        bias[t] = ldf(bfc1, t * 16 + m, isbf);
        w2v[t] = ldf(Wfc2, t * 16 + m, isbf);
    }
    float b2s = ldf(bfc2, 0, isbf);
    floatx4 zero = {0.f, 0.f, 0.f, 0.f};

    const int nTiles = NC / 16;
    int nWaves = (gridDim.x * blockDim.x) >> 6;

    for (int base = wid * 2; base < nTiles; base += 2 * nWaves) {
#pragma unroll
        for (int q = 0; q < 2; ++q) {
            int tile = base + q;
            if (tile >= nTiles) break;
            int c = tile * 16 + m;
            int c0, c1;
            if (c64) {
                const long long* cl = (const long long*)cand;
                c0 = (int)cl[2 * c];
                c1 = (int)cl[2 * c + 1];
            } else {
                int2 cc = *(const int2*)((const int*)cand + 2 * c);
                c0 = cc.x;
                c1 = cc.y;
            }
            int row = (half < 2) ? c0 : c1;
            short8 af = *(const short8*)(xs + row * 16 + (half & 1) * 8);
            float part[4] = {0.f, 0.f, 0.f, 0.f};
#pragma unroll
            for (int t = 0; t < 4; ++t) {
                floatx4 ac = __builtin_amdgcn_mfma_f32_16x16x32_bf16(af, bfrag[t], zero, 0, 0, 0);
#pragma unroll
                for (int r = 0; r < 4; ++r) {
                    float hvv = selu_f(ac[r] + bias[t]);
                    part[r] = fmaf(hvv, w2v[t], part[r]);
                }
            }
#pragma unroll
            for (int off = 1; off < 16; off <<= 1) {
#pragma unroll
                for (int r = 0; r < 4; ++r)
                    part[r] += __shfl_xor(part[r], off, 64);
            }
            if (m == 0) {
                if (isbf) {
                    ushort4 o;
                    o.x = f2bfbits(part[0] + b2s);
                    o.y = f2bfbits(part[1] + b2s);
                    o.z = f2bfbits(part[2] + b2s);
                    o.w = f2bfbits(part[3] + b2s);
                    *(ushort4*)((unsigned short*)out + tile * 16 + half * 4) = o;
                } else {
                    float4 o = make_float4(part[0] + b2s, part[1] + b2s,
                                           part[2] + b2s, part[3] + b2s);
                    *(float4*)((float*)out + tile * 16 + half * 4) = o;
                }
            }
        }
    }
}

extern "C" void kernel_launch(void* const* d_in, const int* in_sizes, int n_in,
                              void* d_out, int out_size, void* d_ws, size_t ws_size,
                              hipStream_t stream) {
    const void* x_u = d_in[0];
    const void* x_g = d_in[1];
    const void* cand = d_in[2];
    const void* edges = d_in[3];
    const void* W1r = d_in[4];
    const void* W1o = d_in[5];
    const void* b1 = d_in[6];
    const void* W2r = d_in[7];
    const void* W2o = d_in[8];
    const void* b2 = d_in[9];
    const void* Wun = d_in[10];
    const void* bun = d_in[11];
    const void* Wfc1 = d_in[12];
    const void* bfc1 = d_in[13];
    const void* Wfc2 = d_in[14];
    const void* bfc2 = d_in[15];

    char* ws = (char*)d_ws;
    int* flags = (int*)ws;                                  // 64 B
    int* gcur = (int*)(ws + 64);                            // 4 KB
    unsigned int* glist = (unsigned int*)(ws + 4160);       // 16.01 MB
    size_t glist_bytes = (size_t)NBK * CAP * 4;             // 16010240
    char* p = ws + 4160 + glist_bytes;
    int* dstoff = (int*)p;                                  // 400 KB
    int* ddeg = (int*)(p + 400000);                         // 400 KB
    ushortx8* hbf = (ushortx8*)(p + 800000);                // 1.6 MB
    unsigned short* xs = (unsigned short*)(p + 2400000);    // 6.4 MB
    float4* pagg1 = (float4*)(p + 8800000);                 // 1.6 MB
    float4* pagg2 = (float4*)(p + 10400000);                // 3.2 MB

    hipMemsetAsync(gcur, 0, NBKP * 4, stream);

    k_detect<<<1, 64, 0, stream>>>((const unsigned int*)x_u,
                                   (const unsigned int*)cand,
                                   (const unsigned int*)edges, flags);
    k_bin<<<(NE + CHUNK - 1) / CHUNK, 256, 0, stream>>>(edges, gcur, glist, flags);
    k_sort<<<NBK, 256, 0, stream>>>(gcur, glist, dstoff, ddeg);
    k_gather1<<<(8 * NG + 255) / 256, 256, 0, stream>>>(dstoff, ddeg, glist, x_g,
                                                        pagg1, flags);
    k_node1<<<(NG + 255) / 256, 256, 0, stream>>>(pagg1, x_g, W1r, W1o, b1, hbf, flags);
    k_gather2<<<(8 * NG + 255) / 256, 256, 0, stream>>>(dstoff, ddeg, glist, hbf,
                                                        pagg2, flags);
    k_node2<<<(NG + 255) / 256, 256, 0, stream>>>(pagg2, hbf, W2r, W2o, b2, xs, flags);
    k_unconn<<<(NU + 255) / 256, 256, 0, stream>>>(x_u, Wun, bun, xs, flags);
    k_fc<<<2048, 256, 0, stream>>>(xs, cand, Wfc1, bfc1, Wfc2, bfc2, d_out, flags);
}

// Round 11
// 322.406 us; speedup vs baseline: 1.0774x; 1.0774x over previous
//
#include <hip/hip_runtime.h>
#include <hip/hip_bf16.h>

#define NG 100000
#define NU 100000
#define NE 3200000
#define NC 2000000

// dst-bucket binning: 128 dsts per bucket
#define BSZ 128
#define NBK 782          // ceil(NG/BSZ)
#define NBKP 800         // padded array size
#define CAP 5120         // entries per bucket (mean 4096, +16 sigma)
#define CHUNK 8192       // edges per k_bin block (longer phase-D runs = fewer
                         // partial sectors; scatter-write bytes are the clock)

typedef __attribute__((ext_vector_type(8))) short short8;
typedef __attribute__((ext_vector_type(4))) float floatx4;
typedef unsigned short ushortx8 __attribute__((ext_vector_type(8)));

// branchless SELU on the HW transcendental (6 VALU ops)
__device__ __forceinline__ float selu_f(float x) {
    const float LAM = 1.0507009873554805f;
    const float ALA = 1.7580993408473766f;  // LAM * ALPHA
    const float L2E = 1.44269504088896340736f;
    float e = __builtin_amdgcn_exp2f(fminf(x, 0.f) * L2E);
    return fmaf(LAM, fmaxf(x, 0.f), fmaf(ALA, e, -ALA));
}

__device__ __forceinline__ float bfbits2f(unsigned short u) {
    return __uint_as_float(((unsigned)u) << 16);
}

__device__ __forceinline__ unsigned short f2bfbits(float f) {
    union { __hip_bfloat16 h; unsigned short u; } cv;
    cv.h = __float2bfloat16(f);
    return cv.u;
}

__device__ __forceinline__ float ldf(const void* p, int i, int isbf) {
    return isbf ? bfbits2f(((const unsigned short*)p)[i]) : ((const float*)p)[i];
}

// ---- dtype detection: flags[0]=floats-are-bf16, flags[1]=cand-is-i64,
//      flags[2]=edges-is-i64 ------------------------------------------------
__global__ void k_detect(const unsigned int* __restrict__ xw,
                         const unsigned int* __restrict__ cw,
                         const unsigned int* __restrict__ ew,
                         int* __restrict__ flags) {
    if (threadIdx.x != 0 || blockIdx.x != 0) return;
    int nb = 0;
    for (int i = 0; i < 64; ++i) {
        unsigned lo = xw[i] & 0xffffu;
        unsigned e = (lo >> 7) & 0xff;
        if (e >= 112 && e <= 134) ++nb;
    }
    flags[0] = (nb >= 32) ? 1 : 0;
    int cz = 0, ez = 0;
    for (int i = 0; i < 64; ++i) {
        if (cw[2 * i + 1] == 0u) ++cz;
        if (ew[2 * i + 1] == 0u) ++ez;
    }
    flags[1] = (cz >= 48) ? 1 : 0;
    flags[2] = (ez >= 48) ? 1 : 0;
}

__device__ __forceinline__ void ld_edge(const void* edges, long long e, int e64,
                                        int& s, int& d) {
    if (e64) {
        const long long* el = (const long long*)edges;
        s = (int)el[e];
        d = (int)el[NE + e];
    } else {
        const int* ei = (const int*)edges;
        s = ei[e];
        d = ei[NE + e];
    }
}

// ---- Bucket-sorted edge build with COALESCED writes -----------------------
__global__ __launch_bounds__(256) void k_bin(const void* __restrict__ edges,
        int* __restrict__ gcur, unsigned int* __restrict__ glist,
        const int* __restrict__ flags) {
    __shared__ unsigned int ord[CHUNK];        // 32 KB
    __shared__ unsigned short ordb[CHUNK];     // 16 KB
    __shared__ int hist[NBKP];
    __shared__ int lstart[NBKP];
    __shared__ int ofs[NBKP];
    __shared__ int gbase[NBKP];
    __shared__ int psum[256];                  // total ~62 KB -> 2 blocks/CU

    int tid = threadIdx.x;
    long long base = (long long)blockIdx.x * CHUNK;
    int chunk = (int)(NE - base);
    if (chunk > CHUNK) chunk = CHUNK;
    int e64 = flags[2];

    for (int b = tid; b < NBKP; b += 256) hist[b] = 0;
    __syncthreads();

    // phase A: histogram
    for (int i = 0; i < CHUNK / 256; ++i) {
        int idx = i * 256 + tid;
        if (idx < chunk) {
            int s, d;
            ld_edge(edges, base + idx, e64, s, d);
            atomicAdd(&hist[d >> 7], 1);
        }
    }
    __syncthreads();

    // phase B: exclusive scan + global range reservation
    int bb = tid * 4;
    int h0 = (bb + 0 < NBKP) ? hist[bb + 0] : 0;
    int h1 = (bb + 1 < NBKP) ? hist[bb + 1] : 0;
    int h2 = (bb + 2 < NBKP) ? hist[bb + 2] : 0;
    int h3 = (bb + 3 < NBKP) ? hist[bb + 3] : 0;
    int tsum = h0 + h1 + h2 + h3;
    psum[tid] = tsum;
    __syncthreads();
    for (int off = 1; off < 256; off <<= 1) {
        int v = (tid >= off) ? psum[tid - off] : 0;
        __syncthreads();
        psum[tid] += v;
        __syncthreads();
    }
    int excl = psum[tid] - tsum;
    if (bb + 0 < NBKP) { lstart[bb + 0] = excl; }
    if (bb + 1 < NBKP) { lstart[bb + 1] = excl + h0; }
    if (bb + 2 < NBKP) { lstart[bb + 2] = excl + h0 + h1; }
    if (bb + 3 < NBKP) { lstart[bb + 3] = excl + h0 + h1 + h2; }
    for (int k = 0; k < 4; ++k) {
        int b = bb + k;
        if (b < NBKP) {
            int c = hist[b];
            int g = 0;
            if (c > 0 && b < NBK) g = atomicAdd(&gcur[b], c);
            gbase[b] = g;
            ofs[b] = lstart[b];
        }
    }
    __syncthreads();

    // phase C: reorder by bucket into LDS
    for (int i = 0; i < CHUNK / 256; ++i) {
        int idx = i * 256 + tid;
        if (idx < chunk) {
            int s, d;
            ld_edge(edges, base + idx, e64, s, d);
            int b = d >> 7;
            int pos = atomicAdd(&ofs[b], 1);
            ord[pos] = ((unsigned)s << 7) | (unsigned)(d & 127);
            ordb[pos] = (unsigned short)b;
        }
    }
    __syncthreads();

    // phase D: coalesced write-out
    for (int i = 0; i < CHUNK / 256; ++i) {
        int idx = i * 256 + tid;
        if (idx < chunk) {
            int b = ordb[idx];
            int p = gbase[b] + (idx - lstart[b]);
            if (p < CAP) glist[(long long)b * CAP + p] = ord[idx];
        }
    }
}

// ---- Counting-sort each bucket by dl, in place; emit per-dst CSR ----------
__global__ __launch_bounds__(256) void k_sort(const int* __restrict__ gcur,
        unsigned int* __restrict__ glist,
        int* __restrict__ dstoff, int* __restrict__ ddeg) {
    __shared__ unsigned int sorted[CAP];   // 20 KB
    __shared__ int hist[BSZ];
    __shared__ int incl[BSZ];
    __shared__ int cur[BSZ];
    int b = blockIdx.x;
    int tid = threadIdx.x;
    int cnt = gcur[b];
    if (cnt > CAP) cnt = CAP;
    unsigned int* lp = glist + (long long)b * CAP;

    if (tid < BSZ) hist[tid] = 0;
    __syncthreads();
    for (int k = tid; k < cnt; k += 256)
        atomicAdd(&hist[lp[k] & 127], 1);
    __syncthreads();
    if (tid < BSZ) incl[tid] = hist[tid];
    __syncthreads();
    for (int off = 1; off < BSZ; off <<= 1) {
        int v = (tid < BSZ && tid >= off) ? incl[tid - off] : 0;
        __syncthreads();
        if (tid < BSZ && tid >= off) incl[tid] += v;
        __syncthreads();
    }
    if (tid < BSZ) {
        int excl = incl[tid] - hist[tid];
        cur[tid] = excl;
        int d = b * BSZ + tid;
        if (d < NG) {
            dstoff[d] = b * CAP + excl;
            ddeg[d] = hist[tid];
        }
    }
    __syncthreads();
    for (int k = tid; k < cnt; k += 256) {
        unsigned u = lp[k];
        int pos = atomicAdd(&cur[u & 127], 1);
        sorted[pos] = u >> 7;
    }
    __syncthreads();
    for (int k = tid; k < cnt; k += 256) lp[k] = sorted[k];
}

// ---- Gather 1: 8 threads/dst, slim (high occupancy), partials to pagg1 ----
__global__ __launch_bounds__(256) void k_gather1(const int* __restrict__ dstoff,
        const int* __restrict__ ddeg, const unsigned int* __restrict__ glist,
        const void* __restrict__ xg, float4* __restrict__ pagg1,
        const int* __restrict__ flags) {
    int gid = blockIdx.x * 256 + threadIdx.x;
    int d = gid >> 3;
    if (d >= NG) return;
    int q = gid & 7;
    int isbf = flags[0];
    int start = dstoff[d];
    int deg = ddeg[d];
    float a0 = 0.f, a1 = 0.f, a2 = 0.f, a3 = 0.f;
    for (int k = q; k < deg; k += 8) {
        int s = glist[start + k];
        if (isbf) {
            ushort4 r = *(const ushort4*)((const unsigned short*)xg + s * 4);
            a0 += bfbits2f(r.x); a1 += bfbits2f(r.y);
            a2 += bfbits2f(r.z); a3 += bfbits2f(r.w);
        } else {
            float4 r = *(const float4*)((const float*)xg + s * 4);
            a0 += r.x; a1 += r.y; a2 += r.z; a3 += r.w;
        }
    }
#pragma unroll
    for (int off = 1; off < 8; off <<= 1) {
        a0 += __shfl_xor(a0, off);
        a1 += __shfl_xor(a1, off);
        a2 += __shfl_xor(a2, off);
        a3 += __shfl_xor(a3, off);
    }
    if (q == 0) pagg1[d] = make_float4(a0, a1, a2, a3);
}

// ---- Node 1: MLP -> hbf (bf16) --------------------------------------------
__global__ __launch_bounds__(256) void k_node1(const float4* __restrict__ pagg1,
        const void* __restrict__ xg,
        const void* __restrict__ W1r, const void* __restrict__ W1o,
        const void* __restrict__ b1, ushortx8* __restrict__ hbf,
        const int* __restrict__ flags) {
    int d = blockIdx.x * 256 + threadIdx.x;
    if (d >= NG) return;
    int isbf = flags[0];
    float4 av = pagg1[d];
    float a[4] = {av.x, av.y, av.z, av.w};
    float x[4];
#pragma unroll
    for (int c = 0; c < 4; ++c) x[c] = ldf(xg, d * 4 + c, isbf);
    ushortx8 o;
#pragma unroll
    for (int j = 0; j < 8; ++j) {
        float v = ldf(b1, j, isbf);
#pragma unroll
        for (int c = 0; c < 4; ++c)
            v += a[c] * ldf(W1r, c * 8 + j, isbf)
               + x[c] * ldf(W1o, c * 8 + j, isbf);
        o[j] = f2bfbits(selu_f(v));
    }
    hbf[d] = o;
}

// ---- Gather 2: 8 threads/dst, slim, partials to pagg2 ---------------------
__global__ __launch_bounds__(256) void k_gather2(const int* __restrict__ dstoff,
        const int* __restrict__ ddeg, const unsigned int* __restrict__ glist,
        const ushortx8* __restrict__ hbf, float4* __restrict__ pagg2,
        const int* __restrict__ flags) {
    int gid = blockIdx.x * 256 + threadIdx.x;
    int d = gid >> 3;
    if (d >= NG) return;
    int q = gid & 7;
    int start = dstoff[d];
    int deg = ddeg[d];
    float a[8] = {0.f, 0.f, 0.f, 0.f, 0.f, 0.f, 0.f, 0.f};
    for (int k = q; k < deg; k += 8) {
        int s = glist[start + k];
        ushortx8 r = hbf[s];
#pragma unroll
        for (int c = 0; c < 8; ++c) a[c] += bfbits2f((unsigned short)r[c]);
    }
#pragma unroll
    for (int off = 1; off < 8; off <<= 1) {
#pragma unroll
        for (int c = 0; c < 8; ++c) a[c] += __shfl_xor(a[c], off);
    }
    if (q == 0) {
        pagg2[2 * d + 0] = make_float4(a[0], a[1], a[2], a[3]);
        pagg2[2 * d + 1] = make_float4(a[4], a[5], a[6], a[7]);
    }
}

// ---- Node 2: MLP -> xs (bf16) ---------------------------------------------
__global__ __launch_bounds__(256) void k_node2(const float4* __restrict__ pagg2,
        const ushortx8* __restrict__ hbf,
        const void* __restrict__ W2r, const void* __restrict__ W2o,
        const void* __restrict__ b2, unsigned short* __restrict__ xs,
        const int* __restrict__ flags) {
    int d = blockIdx.x * 256 + threadIdx.x;
    if (d >= NG) return;
    int isbf = flags[0];
    float4 p0 = pagg2[2 * d + 0];
    float4 p1 = pagg2[2 * d + 1];
    float a[8] = {p0.x, p0.y, p0.z, p0.w, p1.x, p1.y, p1.z, p1.w};
    ushortx8 hr = hbf[d];
    float hv[8];
#pragma unroll
    for (int c = 0; c < 8; ++c) hv[c] = bfbits2f((unsigned short)hr[c]);
    ushortx8 lo, hi;
#pragma unroll
    for (int j = 0; j < 16; ++j) {
        float v = ldf(b2, j, isbf);
#pragma unroll
        for (int c = 0; c < 8; ++c)
            v += a[c] * ldf(W2r, c * 16 + j, isbf)
               + hv[c] * ldf(W2o, c * 16 + j, isbf);
        unsigned short bb16 = f2bfbits(selu_f(v));
        if (j < 8) lo[j] = bb16; else hi[j - 8] = bb16;
    }
    ushortx8* xp = (ushortx8*)(xs + d * 16);
    xp[0] = lo;
    xp[1] = hi;
}

// ---- fc_unconnected -> x_stacked[NG:NG+NU] (bf16), NO selu ----------------
__global__ __launch_bounds__(256) void k_unconn(const void* __restrict__ xu,
        const void* __restrict__ Wun, const void* __restrict__ bun,
        unsigned short* __restrict__ xs, const int* __restrict__ flags) {
    int u = blockIdx.x * 256 + threadIdx.x;
    if (u >= NU) return;
    int isbf = flags[0];
    float x[4];
#pragma unroll
    for (int k = 0; k < 4; ++k) x[k] = ldf(xu, u * 4 + k, isbf);
    ushortx8 lo, hi;
#pragma unroll
    for (int j = 0; j < 16; ++j) {
        float v = ldf(bun, j, isbf);
#pragma unroll
        for (int k = 0; k < 4; ++k)
            v += x[k] * ldf(Wun, k * 16 + j, isbf);
        unsigned short bb = f2bfbits(v);
        if (j < 8) lo[j] = bb; else hi[j - 8] = bb;
    }
    ushortx8* xp = (ushortx8*)(xs + (NG + u) * 16);
    xp[0] = lo;
    xp[1] = hi;
}

__device__ __forceinline__ int2 ld_cand2(const void* cand, int c, int c64) {
    if (c64) {
        const long long* cl = (const long long*)cand;
        return make_int2((int)cl[2 * c], (int)cl[2 * c + 1]);
    }
    return *(const int2*)((const int*)cand + 2 * c);
}

// ---- FC head: persistent waves, software-pipelined gather, MFMA 16x16x32 --
// Pipeline: cand prefetched 2 iters ahead, af row 1 iter ahead, so the
// cand->af->MFMA dependency chain overlaps the previous tile's epilogue.
__global__ __launch_bounds__(256) void k_fc(const unsigned short* __restrict__ xs,
        const void* __restrict__ cand,
        const void* __restrict__ Wfc1, const void* __restrict__ bfc1,
        const void* __restrict__ Wfc2, const void* __restrict__ bfc2,
        void* __restrict__ out, const int* __restrict__ flags) {
    int lane = threadIdx.x & 63;
    int wid = (blockIdx.x * blockDim.x + threadIdx.x) >> 6;
    int m = lane & 15;
    int half = lane >> 4;
    int isbf = flags[0], c64 = flags[1];

    short8 bfrag[4];
#pragma unroll
    for (int t = 0; t < 4; ++t) {
#pragma unroll
        for (int j = 0; j < 8; ++j)
            bfrag[t][j] = (short)f2bfbits(ldf(Wfc1, (half * 8 + j) * 64 + t * 16 + m, isbf));
    }
    float bias[4], w2v[4];
#pragma unroll
    for (int t = 0; t < 4; ++t) {
        bias[t] = ldf(bfc1, t * 16 + m, isbf);
        w2v[t] = ldf(Wfc2, t * 16 + m, isbf);
    }
    float b2s = ldf(bfc2, 0, isbf);
    floatx4 zero = {0.f, 0.f, 0.f, 0.f};

    const int nTiles = NC / 16;
    int nW = (gridDim.x * blockDim.x) >> 6;
    if (wid >= nTiles) return;

    // prologue: cand for tile wid and wid+nW; af for tile wid
    int tn1 = wid + nW;
    int2 cc_cur = ld_cand2(cand, wid * 16 + m, c64);
    int tn1c = (tn1 < nTiles) ? tn1 : wid;
    int2 cc_nxt = ld_cand2(cand, tn1c * 16 + m, c64);
    {
        int row = (half < 2) ? cc_cur.x : cc_cur.y;
        // fallthrough into loop with af_cur loaded
        short8 af_cur = *(const short8*)(xs + row * 16 + (half & 1) * 8);

        for (int t = wid; t < nTiles; t += nW) {
            int tnn = t + 2 * nW;
            int tnnc = (tnn < nTiles) ? tnn : t;
            // prefetch cand 2 ahead (independent of everything below)
            int2 cc_n2 = ld_cand2(cand, tnnc * 16 + m, c64);
            // prefetch af 1 ahead (depends only on cc_nxt, loaded last iter)
            int rown = (half < 2) ? cc_nxt.x : cc_nxt.y;
            short8 af_nxt = *(const short8*)(xs + rown * 16 + (half & 1) * 8);

            // compute tile t
            float part[4] = {0.f, 0.f, 0.f, 0.f};
#pragma unroll
            for (int tt = 0; tt < 4; ++tt) {
                floatx4 ac = __builtin_amdgcn_mfma_f32_16x16x32_bf16(af_cur, bfrag[tt], zero, 0, 0, 0);
#pragma unroll
                for (int r = 0; r < 4; ++r) {
                    float hvv = selu_f(ac[r] + bias[tt]);
                    part[r] = fmaf(hvv, w2v[tt], part[r]);
                }
            }
#pragma unroll
            for (int off = 1; off < 16; off <<= 1) {
#pragma unroll
                for (int r = 0; r < 4; ++r)
                    part[r] += __shfl_xor(part[r], off, 64);
            }
            if (m == 0) {
                if (isbf) {
                    ushort4 o;
                    o.x = f2bfbits(part[0] + b2s);
                    o.y = f2bfbits(part[1] + b2s);
                    o.z = f2bfbits(part[2] + b2s);
                    o.w = f2bfbits(part[3] + b2s);
                    *(ushort4*)((unsigned short*)out + t * 16 + half * 4) = o;
                } else {
                    float4 o = make_float4(part[0] + b2s, part[1] + b2s,
                                           part[2] + b2s, part[3] + b2s);
                    *(float4*)((float*)out + t * 16 + half * 4) = o;
                }
            }
            // rotate pipeline
            cc_nxt = cc_n2;
            af_cur = af_nxt;
        }
    }
}

extern "C" void kernel_launch(void* const* d_in, const int* in_sizes, int n_in,
                              void* d_out, int out_size, void* d_ws, size_t ws_size,
                              hipStream_t stream) {
    const void* x_u = d_in[0];
    const void* x_g = d_in[1];
    const void* cand = d_in[2];
    const void* edges = d_in[3];
    const void* W1r = d_in[4];
    const void* W1o = d_in[5];
    const void* b1 = d_in[6];
    const void* W2r = d_in[7];
    const void* W2o = d_in[8];
    const void* b2 = d_in[9];
    const void* Wun = d_in[10];
    const void* bun = d_in[11];
    const void* Wfc1 = d_in[12];
    const void* bfc1 = d_in[13];
    const void* Wfc2 = d_in[14];
    const void* bfc2 = d_in[15];

    char* ws = (char*)d_ws;
    int* flags = (int*)ws;                                  // 64 B
    int* gcur = (int*)(ws + 64);                            // 4 KB
    unsigned int* glist = (unsigned int*)(ws + 4160);       // 16.01 MB
    size_t glist_bytes = (size_t)NBK * CAP * 4;             // 16010240
    char* p = ws + 4160 + glist_bytes;
    int* dstoff = (int*)p;                                  // 400 KB
    int* ddeg = (int*)(p + 400000);                         // 400 KB
    ushortx8* hbf = (ushortx8*)(p + 800000);                // 1.6 MB
    unsigned short* xs = (unsigned short*)(p + 2400000);    // 6.4 MB
    float4* pagg1 = (float4*)(p + 8800000);                 // 1.6 MB
    float4* pagg2 = (float4*)(p + 10400000);                // 3.2 MB

    hipMemsetAsync(gcur, 0, NBKP * 4, stream);

    k_detect<<<1, 64, 0, stream>>>((const unsigned int*)x_u,
                                   (const unsigned int*)cand,
                                   (const unsigned int*)edges, flags);
    k_bin<<<(NE + CHUNK - 1) / CHUNK, 256, 0, stream>>>(edges, gcur, glist, flags);
    k_sort<<<NBK, 256, 0, stream>>>(gcur, glist, dstoff, ddeg);
    k_gather1<<<(8 * NG + 255) / 256, 256, 0, stream>>>(dstoff, ddeg, glist, x_g,
                                                        pagg1, flags);
    k_node1<<<(NG + 255) / 256, 256, 0, stream>>>(pagg1, x_g, W1r, W1o, b1, hbf, flags);
    k_gather2<<<(8 * NG + 255) / 256, 256, 0, stream>>>(dstoff, ddeg, glist, hbf,
                                                        pagg2, flags);
    k_node2<<<(NG + 255) / 256, 256, 0, stream>>>(pagg2, hbf, W2r, W2o, b2, xs, flags);
    k_unconn<<<(NU + 255) / 256, 256, 0, stream>>>(x_u, Wun, bun, xs, flags);
    k_fc<<<2048, 256, 0, stream>>>(xs, cand, Wfc1, bfc1, Wfc2, bfc2, d_out, flags);
}

// Round 12
// 317.409 us; speedup vs baseline: 1.0944x; 1.0157x over previous
//
#include <hip/hip_runtime.h>
#include <hip/hip_bf16.h>

#define NG 100000
#define NU 100000
#define NE 3200000
#define NC 2000000

// dst-bucket binning: 128 dsts per bucket
#define BSZ 128
#define NBK 782          // ceil(NG/BSZ)
#define CAP 5120         // entries per fine bucket (mean 4096, +16 sigma)

// two-level binning: 61 super-buckets of 13 fine buckets (61*13=793>=782)
#define NSUP 61
#define SFB 13
#define SSPAN (SFB * BSZ)   // 1664 dsts per super
#define SCAP 56320          // entries per super (mean 52459, +17 sigma)
#define SCHUNK 8192         // edges per binning block

typedef __attribute__((ext_vector_type(8))) short short8;
typedef __attribute__((ext_vector_type(4))) float floatx4;
typedef unsigned short ushortx8 __attribute__((ext_vector_type(8)));

// branchless SELU on the HW transcendental (6 VALU ops)
__device__ __forceinline__ float selu_f(float x) {
    const float LAM = 1.0507009873554805f;
    const float ALA = 1.7580993408473766f;  // LAM * ALPHA
    const float L2E = 1.44269504088896340736f;
    float e = __builtin_amdgcn_exp2f(fminf(x, 0.f) * L2E);
    return fmaf(LAM, fmaxf(x, 0.f), fmaf(ALA, e, -ALA));
}

__device__ __forceinline__ float bfbits2f(unsigned short u) {
    return __uint_as_float(((unsigned)u) << 16);
}

__device__ __forceinline__ unsigned short f2bfbits(float f) {
    union { __hip_bfloat16 h; unsigned short u; } cv;
    cv.h = __float2bfloat16(f);
    return cv.u;
}

__device__ __forceinline__ float ldf(const void* p, int i, int isbf) {
    return isbf ? bfbits2f(((const unsigned short*)p)[i]) : ((const float*)p)[i];
}

// ---- dtype detection ------------------------------------------------------
__global__ void k_detect(const unsigned int* __restrict__ xw,
                         const unsigned int* __restrict__ cw,
                         const unsigned int* __restrict__ ew,
                         int* __restrict__ flags) {
    if (threadIdx.x != 0 || blockIdx.x != 0) return;
    int nb = 0;
    for (int i = 0; i < 64; ++i) {
        unsigned lo = xw[i] & 0xffffu;
        unsigned e = (lo >> 7) & 0xff;
        if (e >= 112 && e <= 134) ++nb;
    }
    flags[0] = (nb >= 32) ? 1 : 0;
    int cz = 0, ez = 0;
    for (int i = 0; i < 64; ++i) {
        if (cw[2 * i + 1] == 0u) ++cz;
        if (ew[2 * i + 1] == 0u) ++ez;
    }
    flags[1] = (cz >= 48) ? 1 : 0;
    flags[2] = (ez >= 48) ? 1 : 0;
}

__device__ __forceinline__ void ld_edge(const void* edges, long long e, int e64,
                                        int& s, int& d) {
    if (e64) {
        const long long* el = (const long long*)edges;
        s = (int)el[e];
        d = (int)el[NE + e];
    } else {
        const int* ei = (const int*)edges;
        s = ei[e];
        d = ei[NE + e];
    }
}

// ---- Binning pass 1: edges -> 61 super-buckets (runs ~134 -> coalesced) ---
// slist entry: (s << 11) | (d - sup*SSPAN)   [17+11 = 28 bits]
__global__ __launch_bounds__(256) void k_bin1(const void* __restrict__ edges,
        int* __restrict__ scur, unsigned int* __restrict__ slist,
        const int* __restrict__ flags) {
    __shared__ unsigned int ord[SCHUNK];       // 32 KB
    __shared__ unsigned char osup[SCHUNK];     // 8 KB
    __shared__ int hist[64];
    __shared__ int lstart[64];
    __shared__ int ofs[64];
    __shared__ int gbase[64];

    int tid = threadIdx.x;
    long long base = (long long)blockIdx.x * SCHUNK;
    int chunk = (int)(NE - base);
    if (chunk > SCHUNK) chunk = SCHUNK;
    int e64 = flags[2];

    if (tid < 64) hist[tid] = 0;
    __syncthreads();

    // phase A: histogram over supers
    for (int i = 0; i < SCHUNK / 256; ++i) {
        int idx = i * 256 + tid;
        if (idx < chunk) {
            int s, d;
            ld_edge(edges, base + idx, e64, s, d);
            atomicAdd(&hist[d / SSPAN], 1);
        }
    }
    __syncthreads();

    // phase B: serial exclusive scan (61 entries) + global reservation
    if (tid == 0) {
        int run = 0;
        for (int b = 0; b < NSUP; ++b) {
            lstart[b] = run;
            run += hist[b];
        }
    }
    __syncthreads();
    if (tid < NSUP) {
        int c = hist[tid];
        int g = 0;
        if (c > 0) g = atomicAdd(&scur[tid], c);
        gbase[tid] = g;
        ofs[tid] = lstart[tid];
    }
    __syncthreads();

    // phase C: reorder by super into LDS
    for (int i = 0; i < SCHUNK / 256; ++i) {
        int idx = i * 256 + tid;
        if (idx < chunk) {
            int s, d;
            ld_edge(edges, base + idx, e64, s, d);
            int sup = d / SSPAN;
            int pos = atomicAdd(&ofs[sup], 1);
            ord[pos] = ((unsigned)s << 11) | (unsigned)(d - sup * SSPAN);
            osup[pos] = (unsigned char)sup;
        }
    }
    __syncthreads();

    // phase D: coalesced write-out (runs ~134 entries)
    for (int i = 0; i < SCHUNK / 256; ++i) {
        int idx = i * 256 + tid;
        if (idx < chunk) {
            int sup = osup[idx];
            int p = gbase[sup] + (idx - lstart[sup]);
            if (p < SCAP) slist[(long long)sup * SCAP + p] = ord[idx];
        }
    }
}

#define SCH2 ((SCAP + SCHUNK - 1) / SCHUNK)   // 7 chunks per super

// ---- Binning pass 2: super -> 13 fine buckets (runs ~630 -> coalesced) ----
// glist entry: (s << 7) | (d & 127)
__global__ __launch_bounds__(256) void k_bin2(const int* __restrict__ scur,
        const unsigned int* __restrict__ slist,
        int* __restrict__ gcur, unsigned int* __restrict__ glist) {
    __shared__ unsigned int ord[SCHUNK];       // 32 KB
    __shared__ unsigned char ofid[SCHUNK];     // 8 KB
    __shared__ int hist[16];
    __shared__ int lstart[16];
    __shared__ int ofs[16];
    __shared__ int gbase[16];

    int tid = threadIdx.x;
    int sup = blockIdx.x / SCH2;
    int ch = blockIdx.x % SCH2;
    int scnt = scur[sup];
    if (scnt > SCAP) scnt = SCAP;
    int start = ch * SCHUNK;
    int cnt = scnt - start;
    if (cnt <= 0) return;
    if (cnt > SCHUNK) cnt = SCHUNK;
    const unsigned int* sp = slist + (long long)sup * SCAP + start;

    if (tid < 16) hist[tid] = 0;
    __syncthreads();

    // phase A: histogram over fine buckets
    for (int i = 0; i < SCHUNK / 256; ++i) {
        int idx = i * 256 + tid;
        if (idx < cnt) {
            unsigned u = sp[idx];
            atomicAdd(&hist[(u & 2047) >> 7], 1);
        }
    }
    __syncthreads();

    // phase B: serial scan (13) + global reservation
    if (tid == 0) {
        int run = 0;
        for (int b = 0; b < SFB; ++b) {
            lstart[b] = run;
            run += hist[b];
        }
    }
    __syncthreads();
    if (tid < SFB) {
        int c = hist[tid];
        int g = 0;
        int bf = sup * SFB + tid;
        if (c > 0 && bf < NBK) g = atomicAdd(&gcur[bf], c);
        gbase[tid] = g;
        ofs[tid] = lstart[tid];
    }
    __syncthreads();

    // phase C: reorder by fine bucket into LDS
    for (int i = 0; i < SCHUNK / 256; ++i) {
        int idx = i * 256 + tid;
        if (idx < cnt) {
            unsigned u = sp[idx];
            int dl = u & 2047;
            int f = dl >> 7;
            int pos = atomicAdd(&ofs[f], 1);
            ord[pos] = ((u >> 11) << 7) | (unsigned)(dl & 127);
            ofid[pos] = (unsigned char)f;
        }
    }
    __syncthreads();

    // phase D: coalesced write-out (runs ~630 entries)
    for (int i = 0; i < SCHUNK / 256; ++i) {
        int idx = i * 256 + tid;
        if (idx < cnt) {
            int f = ofid[idx];
            int bf = sup * SFB + f;
            int p = gbase[f] + (idx - lstart[f]);
            if (p < CAP) glist[(long long)bf * CAP + p] = ord[idx];
        }
    }
}

// ---- Counting-sort each bucket by dl, in place; emit per-dst CSR ----------
__global__ __launch_bounds__(256) void k_sort(const int* __restrict__ gcur,
        unsigned int* __restrict__ glist,
        int* __restrict__ dstoff, int* __restrict__ ddeg) {
    __shared__ unsigned int sorted[CAP];   // 20 KB
    __shared__ int hist[BSZ];
    __shared__ int incl[BSZ];
    __shared__ int cur[BSZ];
    int b = blockIdx.x;
    int tid = threadIdx.x;
    int cnt = gcur[b];
    if (cnt > CAP) cnt = CAP;
    unsigned int* lp = glist + (long long)b * CAP;

    if (tid < BSZ) hist[tid] = 0;
    __syncthreads();
    for (int k = tid; k < cnt; k += 256)
        atomicAdd(&hist[lp[k] & 127], 1);
    __syncthreads();
    if (tid < BSZ) incl[tid] = hist[tid];
    __syncthreads();
    for (int off = 1; off < BSZ; off <<= 1) {
        int v = (tid < BSZ && tid >= off) ? incl[tid - off] : 0;
        __syncthreads();
        if (tid < BSZ && tid >= off) incl[tid] += v;
        __syncthreads();
    }
    if (tid < BSZ) {
        int excl = incl[tid] - hist[tid];
        cur[tid] = excl;
        int d = b * BSZ + tid;
        if (d < NG) {
            dstoff[d] = b * CAP + excl;
            ddeg[d] = hist[tid];
        }
    }
    __syncthreads();
    for (int k = tid; k < cnt; k += 256) {
        unsigned u = lp[k];
        int pos = atomicAdd(&cur[u & 127], 1);
        sorted[pos] = u >> 7;
    }
    __syncthreads();
    for (int k = tid; k < cnt; k += 256) lp[k] = sorted[k];
}

// ---- Gather 1: 8 threads/dst, slim, partials to pagg1 ---------------------
__global__ __launch_bounds__(256) void k_gather1(const int* __restrict__ dstoff,
        const int* __restrict__ ddeg, const unsigned int* __restrict__ glist,
        const void* __restrict__ xg, float4* __restrict__ pagg1,
        const int* __restrict__ flags) {
    int gid = blockIdx.x * 256 + threadIdx.x;
    int d = gid >> 3;
    if (d >= NG) return;
    int q = gid & 7;
    int isbf = flags[0];
    int start = dstoff[d];
    int deg = ddeg[d];
    float a0 = 0.f, a1 = 0.f, a2 = 0.f, a3 = 0.f;
    for (int k = q; k < deg; k += 8) {
        int s = glist[start + k];
        if (isbf) {
            ushort4 r = *(const ushort4*)((const unsigned short*)xg + s * 4);
            a0 += bfbits2f(r.x); a1 += bfbits2f(r.y);
            a2 += bfbits2f(r.z); a3 += bfbits2f(r.w);
        } else {
            float4 r = *(const float4*)((const float*)xg + s * 4);
            a0 += r.x; a1 += r.y; a2 += r.z; a3 += r.w;
        }
    }
#pragma unroll
    for (int off = 1; off < 8; off <<= 1) {
        a0 += __shfl_xor(a0, off);
        a1 += __shfl_xor(a1, off);
        a2 += __shfl_xor(a2, off);
        a3 += __shfl_xor(a3, off);
    }
    if (q == 0) pagg1[d] = make_float4(a0, a1, a2, a3);
}

// ---- Node 1: MLP -> hbf (bf16) --------------------------------------------
__global__ __launch_bounds__(256) void k_node1(const float4* __restrict__ pagg1,
        const void* __restrict__ xg,
        const void* __restrict__ W1r, const void* __restrict__ W1o,
        const void* __restrict__ b1, ushortx8* __restrict__ hbf,
        const int* __restrict__ flags) {
    int d = blockIdx.x * 256 + threadIdx.x;
    if (d >= NG) return;
    int isbf = flags[0];
    float4 av = pagg1[d];
    float a[4] = {av.x, av.y, av.z, av.w};
    float x[4];
#pragma unroll
    for (int c = 0; c < 4; ++c) x[c] = ldf(xg, d * 4 + c, isbf);
    ushortx8 o;
#pragma unroll
    for (int j = 0; j < 8; ++j) {
        float v = ldf(b1, j, isbf);
#pragma unroll
        for (int c = 0; c < 4; ++c)
            v += a[c] * ldf(W1r, c * 8 + j, isbf)
               + x[c] * ldf(W1o, c * 8 + j, isbf);
        o[j] = f2bfbits(selu_f(v));
    }
    hbf[d] = o;
}

// ---- Gather 2: 8 threads/dst, slim, partials to pagg2 ---------------------
__global__ __launch_bounds__(256) void k_gather2(const int* __restrict__ dstoff,
        const int* __restrict__ ddeg, const unsigned int* __restrict__ glist,
        const ushortx8* __restrict__ hbf, float4* __restrict__ pagg2,
        const int* __restrict__ flags) {
    int gid = blockIdx.x * 256 + threadIdx.x;
    int d = gid >> 3;
    if (d >= NG) return;
    int q = gid & 7;
    int start = dstoff[d];
    int deg = ddeg[d];
    float a[8] = {0.f, 0.f, 0.f, 0.f, 0.f, 0.f, 0.f, 0.f};
    for (int k = q; k < deg; k += 8) {
        int s = glist[start + k];
        ushortx8 r = hbf[s];
#pragma unroll
        for (int c = 0; c < 8; ++c) a[c] += bfbits2f((unsigned short)r[c]);
    }
#pragma unroll
    for (int off = 1; off < 8; off <<= 1) {
#pragma unroll
        for (int c = 0; c < 8; ++c) a[c] += __shfl_xor(a[c], off);
    }
    if (q == 0) {
        pagg2[2 * d + 0] = make_float4(a[0], a[1], a[2], a[3]);
        pagg2[2 * d + 1] = make_float4(a[4], a[5], a[6], a[7]);
    }
}

// ---- Node 2: MLP -> xs (bf16) ---------------------------------------------
__global__ __launch_bounds__(256) void k_node2(const float4* __restrict__ pagg2,
        const ushortx8* __restrict__ hbf,
        const void* __restrict__ W2r, const void* __restrict__ W2o,
        const void* __restrict__ b2, unsigned short* __restrict__ xs,
        const int* __restrict__ flags) {
    int d = blockIdx.x * 256 + threadIdx.x;
    if (d >= NG) return;
    int isbf = flags[0];
    float4 p0 = pagg2[2 * d + 0];
    float4 p1 = pagg2[2 * d + 1];
    float a[8] = {p0.x, p0.y, p0.z, p0.w, p1.x, p1.y, p1.z, p1.w};
    ushortx8 hr = hbf[d];
    float hv[8];
#pragma unroll
    for (int c = 0; c < 8; ++c) hv[c] = bfbits2f((unsigned short)hr[c]);
    ushortx8 lo, hi;
#pragma unroll
    for (int j = 0; j < 16; ++j) {
        float v = ldf(b2, j, isbf);
#pragma unroll
        for (int c = 0; c < 8; ++c)
            v += a[c] * ldf(W2r, c * 16 + j, isbf)
               + hv[c] * ldf(W2o, c * 16 + j, isbf);
        unsigned short bb16 = f2bfbits(selu_f(v));
        if (j < 8) lo[j] = bb16; else hi[j - 8] = bb16;
    }
    ushortx8* xp = (ushortx8*)(xs + d * 16);
    xp[0] = lo;
    xp[1] = hi;
}

// ---- fc_unconnected -> x_stacked[NG:NG+NU] (bf16), NO selu ----------------
__global__ __launch_bounds__(256) void k_unconn(const void* __restrict__ xu,
        const void* __restrict__ Wun, const void* __restrict__ bun,
        unsigned short* __restrict__ xs, const int* __restrict__ flags) {
    int u = blockIdx.x * 256 + threadIdx.x;
    if (u >= NU) return;
    int isbf = flags[0];
    float x[4];
#pragma unroll
    for (int k = 0; k < 4; ++k) x[k] = ldf(xu, u * 4 + k, isbf);
    ushortx8 lo, hi;
#pragma unroll
    for (int j = 0; j < 16; ++j) {
        float v = ldf(bun, j, isbf);
#pragma unroll
        for (int k = 0; k < 4; ++k)
            v += x[k] * ldf(Wun, k * 16 + j, isbf);
        unsigned short bb = f2bfbits(v);
        if (j < 8) lo[j] = bb; else hi[j - 8] = bb;
    }
    ushortx8* xp = (ushortx8*)(xs + (NG + u) * 16);
    xp[0] = lo;
    xp[1] = hi;
}

__device__ __forceinline__ int2 ld_cand2(const void* cand, int c, int c64) {
    if (c64) {
        const long long* cl = (const long long*)cand;
        return make_int2((int)cl[2 * c], (int)cl[2 * c + 1]);
    }
    return *(const int2*)((const int*)cand + 2 * c);
}

// ---- FC head: persistent waves, software-pipelined gather, MFMA 16x16x32 --
__global__ __launch_bounds__(256) void k_fc(const unsigned short* __restrict__ xs,
        const void* __restrict__ cand,
        const void* __restrict__ Wfc1, const void* __restrict__ bfc1,
        const void* __restrict__ Wfc2, const void* __restrict__ bfc2,
        void* __restrict__ out, const int* __restrict__ flags) {
    int lane = threadIdx.x & 63;
    int wid = (blockIdx.x * blockDim.x + threadIdx.x) >> 6;
    int m = lane & 15;
    int half = lane >> 4;
    int isbf = flags[0], c64 = flags[1];

    short8 bfrag[4];
#pragma unroll
    for (int t = 0; t < 4; ++t) {
#pragma unroll
        for (int j = 0; j < 8; ++j)
            bfrag[t][j] = (short)f2bfbits(ldf(Wfc1, (half * 8 + j) * 64 + t * 16 + m, isbf));
    }
    float bias[4], w2v[4];
#pragma unroll
    for (int t = 0; t < 4; ++t) {
        bias[t] = ldf(bfc1, t * 16 + m, isbf);
        w2v[t] = ldf(Wfc2, t * 16 + m, isbf);
    }
    float b2s = ldf(bfc2, 0, isbf);
    floatx4 zero = {0.f, 0.f, 0.f, 0.f};

    const int nTiles = NC / 16;
    int nW = (gridDim.x * blockDim.x) >> 6;
    if (wid >= nTiles) return;

    int tn1 = wid + nW;
    int2 cc_cur = ld_cand2(cand, wid * 16 + m, c64);
    int tn1c = (tn1 < nTiles) ? tn1 : wid;
    int2 cc_nxt = ld_cand2(cand, tn1c * 16 + m, c64);
    {
        int row = (half < 2) ? cc_cur.x : cc_cur.y;
        short8 af_cur = *(const short8*)(xs + row * 16 + (half & 1) * 8);

        for (int t = wid; t < nTiles; t += nW) {
            int tnn = t + 2 * nW;
            int tnnc = (tnn < nTiles) ? tnn : t;
            int2 cc_n2 = ld_cand2(cand, tnnc * 16 + m, c64);
            int rown = (half < 2) ? cc_nxt.x : cc_nxt.y;
            short8 af_nxt = *(const short8*)(xs + rown * 16 + (half & 1) * 8);

            float part[4] = {0.f, 0.f, 0.f, 0.f};
#pragma unroll
            for (int tt = 0; tt < 4; ++tt) {
                floatx4 ac = __builtin_amdgcn_mfma_f32_16x16x32_bf16(af_cur, bfrag[tt], zero, 0, 0, 0);
#pragma unroll
                for (int r = 0; r < 4; ++r) {
                    float hvv = selu_f(ac[r] + bias[tt]);
                    part[r] = fmaf(hvv, w2v[tt], part[r]);
                }
            }
#pragma unroll
            for (int off = 1; off < 16; off <<= 1) {
#pragma unroll
                for (int r = 0; r < 4; ++r)
                    part[r] += __shfl_xor(part[r], off, 64);
            }
            if (m == 0) {
                if (isbf) {
                    ushort4 o;
                    o.x = f2bfbits(part[0] + b2s);
                    o.y = f2bfbits(part[1] + b2s);
                    o.z = f2bfbits(part[2] + b2s);
                    o.w = f2bfbits(part[3] + b2s);
                    *(ushort4*)((unsigned short*)out + t * 16 + half * 4) = o;
                } else {
                    float4 o = make_float4(part[0] + b2s, part[1] + b2s,
                                           part[2] + b2s, part[3] + b2s);
                    *(float4*)((float*)out + t * 16 + half * 4) = o;
                }
            }
            cc_nxt = cc_n2;
            af_cur = af_nxt;
        }
    }
}

extern "C" void kernel_launch(void* const* d_in, const int* in_sizes, int n_in,
                              void* d_out, int out_size, void* d_ws, size_t ws_size,
                              hipStream_t stream) {
    const void* x_u = d_in[0];
    const void* x_g = d_in[1];
    const void* cand = d_in[2];
    const void* edges = d_in[3];
    const void* W1r = d_in[4];
    const void* W1o = d_in[5];
    const void* b1 = d_in[6];
    const void* W2r = d_in[7];
    const void* W2o = d_in[8];
    const void* b2 = d_in[9];
    const void* Wun = d_in[10];
    const void* bun = d_in[11];
    const void* Wfc1 = d_in[12];
    const void* bfc1 = d_in[13];
    const void* Wfc2 = d_in[14];
    const void* bfc2 = d_in[15];

    char* ws = (char*)d_ws;
    int* flags = (int*)ws;                                  // 64 B
    int* gcur = (int*)(ws + 64);                            // 782*4 -> 3200 B
    int* scur = (int*)(ws + 3264);                          // 61*4  -> 244 B
    unsigned int* glist = (unsigned int*)(ws + 4160);       // 16.01 MB
    size_t glist_bytes = (size_t)NBK * CAP * 4;             // 16010240
    char* p = ws + 4160 + glist_bytes;
    // slist (13.75 MB) overlaps the post-binning buffers below: it is dead
    // after k_bin2, and dstoff/ddeg/hbf/xs/pagg* are all written later.
    unsigned int* slist = (unsigned int*)p;                 // 61*56320*4 = 13.74 MB
    int* dstoff = (int*)p;                                  // 400 KB
    int* ddeg = (int*)(p + 400000);                         // 400 KB
    ushortx8* hbf = (ushortx8*)(p + 800000);                // 1.6 MB
    unsigned short* xs = (unsigned short*)(p + 2400000);    // 6.4 MB
    float4* pagg1 = (float4*)(p + 8800000);                 // 1.6 MB
    float4* pagg2 = (float4*)(p + 10400000);                // 3.2 MB

    hipMemsetAsync(gcur, 0, 3456, stream);   // zeroes gcur + scur

    k_detect<<<1, 64, 0, stream>>>((const unsigned int*)x_u,
                                   (const unsigned int*)cand,
                                   (const unsigned int*)edges, flags);
    k_bin1<<<(NE + SCHUNK - 1) / SCHUNK, 256, 0, stream>>>(edges, scur, slist, flags);
    k_bin2<<<NSUP * SCH2, 256, 0, stream>>>(scur, slist, gcur, glist);
    k_sort<<<NBK, 256, 0, stream>>>(gcur, glist, dstoff, ddeg);
    k_gather1<<<(8 * NG + 255) / 256, 256, 0, stream>>>(dstoff, ddeg, glist, x_g,
                                                        pagg1, flags);
    k_node1<<<(NG + 255) / 256, 256, 0, stream>>>(pagg1, x_g, W1r, W1o, b1, hbf, flags);
    k_gather2<<<(8 * NG + 255) / 256, 256, 0, stream>>>(dstoff, ddeg, glist, hbf,
                                                        pagg2, flags);
    k_node2<<<(NG + 255) / 256, 256, 0, stream>>>(pagg2, hbf, W2r, W2o, b2, xs, flags);
    k_unconn<<<(NU + 255) / 256, 256, 0, stream>>>(x_u, Wun, bun, xs, flags);
    k_fc<<<2048, 256, 0, stream>>>(xs, cand, Wfc1, bfc1, Wfc2, bfc2, d_out, flags);
}

// Round 13
// 299.077 us; speedup vs baseline: 1.1615x; 1.0613x over previous
//
#include <hip/hip_runtime.h>
#include <hip/hip_bf16.h>

#define NG 100000
#define NU 100000
#define NE 3200000
#define NC 2000000

// dst-bucket binning: 128 dsts per bucket
#define BSZ 128
#define NBK 782          // ceil(NG/BSZ)
#define CAP 5120         // entries per fine bucket (mean 4096, +16 sigma)

// two-level binning: 61 super-buckets of 13 fine buckets (61*13=793>=782)
#define NSUP 61
#define SFB 13
#define SSPAN (SFB * BSZ)   // 1664 dsts per super
#define SCAP 56320          // entries per super (mean 52459, +17 sigma)
#define SCHUNK 8192         // edges per binning block

typedef __attribute__((ext_vector_type(8))) short short8;
typedef __attribute__((ext_vector_type(4))) float floatx4;
typedef unsigned short ushortx8 __attribute__((ext_vector_type(8)));

// branchless SELU on the HW transcendental (6 VALU ops)
__device__ __forceinline__ float selu_f(float x) {
    const float LAM = 1.0507009873554805f;
    const float ALA = 1.7580993408473766f;  // LAM * ALPHA
    const float L2E = 1.44269504088896340736f;
    float e = __builtin_amdgcn_exp2f(fminf(x, 0.f) * L2E);
    return fmaf(LAM, fmaxf(x, 0.f), fmaf(ALA, e, -ALA));
}

__device__ __forceinline__ float bfbits2f(unsigned short u) {
    return __uint_as_float(((unsigned)u) << 16);
}

__device__ __forceinline__ unsigned short f2bfbits(float f) {
    union { __hip_bfloat16 h; unsigned short u; } cv;
    cv.h = __float2bfloat16(f);
    return cv.u;
}

__device__ __forceinline__ float ldf(const void* p, int i, int isbf) {
    return isbf ? bfbits2f(((const unsigned short*)p)[i]) : ((const float*)p)[i];
}

// ---- dtype detection ------------------------------------------------------
__global__ void k_detect(const unsigned int* __restrict__ xw,
                         const unsigned int* __restrict__ cw,
                         const unsigned int* __restrict__ ew,
                         int* __restrict__ flags) {
    if (threadIdx.x != 0 || blockIdx.x != 0) return;
    int nb = 0;
    for (int i = 0; i < 64; ++i) {
        unsigned lo = xw[i] & 0xffffu;
        unsigned e = (lo >> 7) & 0xff;
        if (e >= 112 && e <= 134) ++nb;
    }
    flags[0] = (nb >= 32) ? 1 : 0;
    int cz = 0, ez = 0;
    for (int i = 0; i < 64; ++i) {
        if (cw[2 * i + 1] == 0u) ++cz;
        if (ew[2 * i + 1] == 0u) ++ez;
    }
    flags[1] = (cz >= 48) ? 1 : 0;
    flags[2] = (ez >= 48) ? 1 : 0;
}

__device__ __forceinline__ void ld_edge(const void* edges, long long e, int e64,
                                        int& s, int& d) {
    if (e64) {
        const long long* el = (const long long*)edges;
        s = (int)el[e];
        d = (int)el[NE + e];
    } else {
        const int* ei = (const int*)edges;
        s = ei[e];
        d = ei[NE + e];
    }
}

// ---- Binning pass 1: edges -> 61 super-buckets (runs ~134 -> coalesced) ---
__global__ __launch_bounds__(256) void k_bin1(const void* __restrict__ edges,
        int* __restrict__ scur, unsigned int* __restrict__ slist,
        const int* __restrict__ flags) {
    __shared__ unsigned int ord[SCHUNK];       // 32 KB
    __shared__ unsigned char osup[SCHUNK];     // 8 KB
    __shared__ int hist[64];
    __shared__ int lstart[64];
    __shared__ int ofs[64];
    __shared__ int gbase[64];

    int tid = threadIdx.x;
    long long base = (long long)blockIdx.x * SCHUNK;
    int chunk = (int)(NE - base);
    if (chunk > SCHUNK) chunk = SCHUNK;
    int e64 = flags[2];

    if (tid < 64) hist[tid] = 0;
    __syncthreads();

    for (int i = 0; i < SCHUNK / 256; ++i) {
        int idx = i * 256 + tid;
        if (idx < chunk) {
            int s, d;
            ld_edge(edges, base + idx, e64, s, d);
            atomicAdd(&hist[d / SSPAN], 1);
        }
    }
    __syncthreads();

    if (tid == 0) {
        int run = 0;
        for (int b = 0; b < NSUP; ++b) {
            lstart[b] = run;
            run += hist[b];
        }
    }
    __syncthreads();
    if (tid < NSUP) {
        int c = hist[tid];
        int g = 0;
        if (c > 0) g = atomicAdd(&scur[tid], c);
        gbase[tid] = g;
        ofs[tid] = lstart[tid];
    }
    __syncthreads();

    for (int i = 0; i < SCHUNK / 256; ++i) {
        int idx = i * 256 + tid;
        if (idx < chunk) {
            int s, d;
            ld_edge(edges, base + idx, e64, s, d);
            int sup = d / SSPAN;
            int pos = atomicAdd(&ofs[sup], 1);
            ord[pos] = ((unsigned)s << 11) | (unsigned)(d - sup * SSPAN);
            osup[pos] = (unsigned char)sup;
        }
    }
    __syncthreads();

    for (int i = 0; i < SCHUNK / 256; ++i) {
        int idx = i * 256 + tid;
        if (idx < chunk) {
            int sup = osup[idx];
            int p = gbase[sup] + (idx - lstart[sup]);
            if (p < SCAP) slist[(long long)sup * SCAP + p] = ord[idx];
        }
    }
}

#define SCH2 ((SCAP + SCHUNK - 1) / SCHUNK)   // 7 chunks per super

// ---- Binning pass 2: super -> 13 fine buckets (runs ~630 -> coalesced) ----
__global__ __launch_bounds__(256) void k_bin2(const int* __restrict__ scur,
        const unsigned int* __restrict__ slist,
        int* __restrict__ gcur, unsigned int* __restrict__ glist) {
    __shared__ unsigned int ord[SCHUNK];       // 32 KB
    __shared__ unsigned char ofid[SCHUNK];     // 8 KB
    __shared__ int hist[16];
    __shared__ int lstart[16];
    __shared__ int ofs[16];
    __shared__ int gbase[16];

    int tid = threadIdx.x;
    int sup = blockIdx.x / SCH2;
    int ch = blockIdx.x % SCH2;
    int scnt = scur[sup];
    if (scnt > SCAP) scnt = SCAP;
    int start = ch * SCHUNK;
    int cnt = scnt - start;
    if (cnt <= 0) return;
    if (cnt > SCHUNK) cnt = SCHUNK;
    const unsigned int* sp = slist + (long long)sup * SCAP + start;

    if (tid < 16) hist[tid] = 0;
    __syncthreads();

    for (int i = 0; i < SCHUNK / 256; ++i) {
        int idx = i * 256 + tid;
        if (idx < cnt) {
            unsigned u = sp[idx];
            atomicAdd(&hist[(u & 2047) >> 7], 1);
        }
    }
    __syncthreads();

    if (tid == 0) {
        int run = 0;
        for (int b = 0; b < SFB; ++b) {
            lstart[b] = run;
            run += hist[b];
        }
    }
    __syncthreads();
    if (tid < SFB) {
        int c = hist[tid];
        int g = 0;
        int bf = sup * SFB + tid;
        if (c > 0 && bf < NBK) g = atomicAdd(&gcur[bf], c);
        gbase[tid] = g;
        ofs[tid] = lstart[tid];
    }
    __syncthreads();

    for (int i = 0; i < SCHUNK / 256; ++i) {
        int idx = i * 256 + tid;
        if (idx < cnt) {
            unsigned u = sp[idx];
            int dl = u & 2047;
            int f = dl >> 7;
            int pos = atomicAdd(&ofs[f], 1);
            ord[pos] = ((u >> 11) << 7) | (unsigned)(dl & 127);
            ofid[pos] = (unsigned char)f;
        }
    }
    __syncthreads();

    for (int i = 0; i < SCHUNK / 256; ++i) {
        int idx = i * 256 + tid;
        if (idx < cnt) {
            int f = ofid[idx];
            int bf = sup * SFB + f;
            int p = gbase[f] + (idx - lstart[f]);
            if (p < CAP) glist[(long long)bf * CAP + p] = ord[idx];
        }
    }
}

// ---- Counting-sort each bucket by dl, in place; emit per-dst CSR ----------
__global__ __launch_bounds__(256) void k_sort(const int* __restrict__ gcur,
        unsigned int* __restrict__ glist,
        int* __restrict__ dstoff, int* __restrict__ ddeg) {
    __shared__ unsigned int sorted[CAP];   // 20 KB
    __shared__ int hist[BSZ];
    __shared__ int incl[BSZ];
    __shared__ int cur[BSZ];
    int b = blockIdx.x;
    int tid = threadIdx.x;
    int cnt = gcur[b];
    if (cnt > CAP) cnt = CAP;
    unsigned int* lp = glist + (long long)b * CAP;

    if (tid < BSZ) hist[tid] = 0;
    __syncthreads();
    for (int k = tid; k < cnt; k += 256)
        atomicAdd(&hist[lp[k] & 127], 1);
    __syncthreads();
    if (tid < BSZ) incl[tid] = hist[tid];
    __syncthreads();
    for (int off = 1; off < BSZ; off <<= 1) {
        int v = (tid < BSZ && tid >= off) ? incl[tid - off] : 0;
        __syncthreads();
        if (tid < BSZ && tid >= off) incl[tid] += v;
        __syncthreads();
    }
    if (tid < BSZ) {
        int excl = incl[tid] - hist[tid];
        cur[tid] = excl;
        int d = b * BSZ + tid;
        if (d < NG) {
            dstoff[d] = b * CAP + excl;
            ddeg[d] = hist[tid];
        }
    }
    __syncthreads();
    for (int k = tid; k < cnt; k += 256) {
        unsigned u = lp[k];
        int pos = atomicAdd(&cur[u & 127], 1);
        sorted[pos] = u >> 7;
    }
    __syncthreads();
    for (int k = tid; k < cnt; k += 256) lp[k] = sorted[k];
}

// ---- Gather+Node 1 fused: 8 threads/dst; after butterfly all 8 lanes hold
//      the full sums, lane q computes output j=q of the MLP -> hbf (bf16) ---
__global__ __launch_bounds__(256) void k_gather1(const int* __restrict__ dstoff,
        const int* __restrict__ ddeg, const unsigned int* __restrict__ glist,
        const void* __restrict__ xg,
        const void* __restrict__ W1r, const void* __restrict__ W1o,
        const void* __restrict__ b1, unsigned short* __restrict__ hbf,
        const int* __restrict__ flags) {
    int gid = blockIdx.x * 256 + threadIdx.x;
    int d = gid >> 3;
    if (d >= NG) return;
    int q = gid & 7;
    int isbf = flags[0];
    int start = dstoff[d];
    int deg = ddeg[d];
    float a0 = 0.f, a1 = 0.f, a2 = 0.f, a3 = 0.f;
    for (int k = q; k < deg; k += 8) {
        int s = glist[start + k];
        if (isbf) {
            ushort4 r = *(const ushort4*)((const unsigned short*)xg + s * 4);
            a0 += bfbits2f(r.x); a1 += bfbits2f(r.y);
            a2 += bfbits2f(r.z); a3 += bfbits2f(r.w);
        } else {
            float4 r = *(const float4*)((const float*)xg + s * 4);
            a0 += r.x; a1 += r.y; a2 += r.z; a3 += r.w;
        }
    }
#pragma unroll
    for (int off = 1; off < 8; off <<= 1) {
        a0 += __shfl_xor(a0, off);
        a1 += __shfl_xor(a1, off);
        a2 += __shfl_xor(a2, off);
        a3 += __shfl_xor(a3, off);
    }
    // fused node MLP: lane q -> output j=q
    float a[4] = {a0, a1, a2, a3};
    float v = ldf(b1, q, isbf);
#pragma unroll
    for (int c = 0; c < 4; ++c)
        v += a[c] * ldf(W1r, c * 8 + q, isbf)
           + ldf(xg, d * 4 + c, isbf) * ldf(W1o, c * 8 + q, isbf);
    hbf[d * 8 + q] = f2bfbits(selu_f(v));
}

// ---- Gather+Node 2 fused: lane q computes outputs j=2q,2q+1 -> xs (bf16) --
__global__ __launch_bounds__(256) void k_gather2(const int* __restrict__ dstoff,
        const int* __restrict__ ddeg, const unsigned int* __restrict__ glist,
        const ushortx8* __restrict__ hbf,
        const void* __restrict__ W2r, const void* __restrict__ W2o,
        const void* __restrict__ b2, unsigned short* __restrict__ xs,
        const int* __restrict__ flags) {
    int gid = blockIdx.x * 256 + threadIdx.x;
    int d = gid >> 3;
    if (d >= NG) return;
    int q = gid & 7;
    int isbf = flags[0];
    int start = dstoff[d];
    int deg = ddeg[d];
    float a[8] = {0.f, 0.f, 0.f, 0.f, 0.f, 0.f, 0.f, 0.f};
    for (int k = q; k < deg; k += 8) {
        int s = glist[start + k];
        ushortx8 r = hbf[s];
#pragma unroll
        for (int c = 0; c < 8; ++c) a[c] += bfbits2f((unsigned short)r[c]);
    }
#pragma unroll
    for (int off = 1; off < 8; off <<= 1) {
#pragma unroll
        for (int c = 0; c < 8; ++c) a[c] += __shfl_xor(a[c], off);
    }
    // fused node MLP: lane q -> outputs j=2q, 2q+1
    ushortx8 hr = hbf[d];
    float hv[8];
#pragma unroll
    for (int c = 0; c < 8; ++c) hv[c] = bfbits2f((unsigned short)hr[c]);
    ushort2 o;
#pragma unroll
    for (int jj = 0; jj < 2; ++jj) {
        int j = q * 2 + jj;
        float v = ldf(b2, j, isbf);
#pragma unroll
        for (int c = 0; c < 8; ++c)
            v += a[c] * ldf(W2r, c * 16 + j, isbf)
               + hv[c] * ldf(W2o, c * 16 + j, isbf);
        unsigned short bb = f2bfbits(selu_f(v));
        if (jj == 0) o.x = bb; else o.y = bb;
    }
    *(ushort2*)(xs + d * 16 + q * 2) = o;
}

// ---- fc_unconnected -> x_stacked[NG:NG+NU] (bf16), NO selu ----------------
__global__ __launch_bounds__(256) void k_unconn(const void* __restrict__ xu,
        const void* __restrict__ Wun, const void* __restrict__ bun,
        unsigned short* __restrict__ xs, const int* __restrict__ flags) {
    int u = blockIdx.x * 256 + threadIdx.x;
    if (u >= NU) return;
    int isbf = flags[0];
    float x[4];
#pragma unroll
    for (int k = 0; k < 4; ++k) x[k] = ldf(xu, u * 4 + k, isbf);
    ushortx8 lo, hi;
#pragma unroll
    for (int j = 0; j < 16; ++j) {
        float v = ldf(bun, j, isbf);
#pragma unroll
        for (int k = 0; k < 4; ++k)
            v += x[k] * ldf(Wun, k * 16 + j, isbf);
        unsigned short bb = f2bfbits(v);
        if (j < 8) lo[j] = bb; else hi[j - 8] = bb;
    }
    ushortx8* xp = (ushortx8*)(xs + (NG + u) * 16);
    xp[0] = lo;
    xp[1] = hi;
}

__device__ __forceinline__ int2 ld_cand2(const void* cand, int c, int c64) {
    if (c64) {
        const long long* cl = (const long long*)cand;
        return make_int2((int)cl[2 * c], (int)cl[2 * c + 1]);
    }
    return *(const int2*)((const int*)cand + 2 * c);
}

// ---- FC head: persistent waves, 2-tile pairs + software pipeline ----------
// Each iteration computes a PAIR of independent tiles (ILP across their
// MFMA/selu/shuffle chains) while the next pair's af rows are in flight.
__global__ __launch_bounds__(256) void k_fc(const unsigned short* __restrict__ xs,
        const void* __restrict__ cand,
        const void* __restrict__ Wfc1, const void* __restrict__ bfc1,
        const void* __restrict__ Wfc2, const void* __restrict__ bfc2,
        void* __restrict__ out, const int* __restrict__ flags) {
    int lane = threadIdx.x & 63;
    int wid = (blockIdx.x * blockDim.x + threadIdx.x) >> 6;
    int m = lane & 15;
    int half = lane >> 4;
    int isbf = flags[0], c64 = flags[1];

    short8 bfrag[4];
#pragma unroll
    for (int t = 0; t < 4; ++t) {
#pragma unroll
        for (int j = 0; j < 8; ++j)
            bfrag[t][j] = (short)f2bfbits(ldf(Wfc1, (half * 8 + j) * 64 + t * 16 + m, isbf));
    }
    float bias[4], w2v[4];
#pragma unroll
    for (int t = 0; t < 4; ++t) {
        bias[t] = ldf(bfc1, t * 16 + m, isbf);
        w2v[t] = ldf(Wfc2, t * 16 + m, isbf);
    }
    float b2s = ldf(bfc2, 0, isbf);
    floatx4 zero = {0.f, 0.f, 0.f, 0.f};

    const int nTiles = NC / 16;
    int nW = (gridDim.x * blockDim.x) >> 6;
    if (wid >= nTiles) return;
    int step = 2 * nW;

    // clamp helper: invalid tiles read tile 0 (valid memory), stores guarded
#define TCL(t) (((t) < nTiles) ? (t) : 0)

    int2 ccA = ld_cand2(cand, TCL(wid) * 16 + m, c64);
    int2 ccB = ld_cand2(cand, TCL(wid + nW) * 16 + m, c64);
    short8 afA = *(const short8*)(xs + ((half < 2) ? ccA.x : ccA.y) * 16 + (half & 1) * 8);
    short8 afB = *(const short8*)(xs + ((half < 2) ? ccB.x : ccB.y) * 16 + (half & 1) * 8);
    int2 ccA1 = ld_cand2(cand, TCL(wid + step) * 16 + m, c64);
    int2 ccB1 = ld_cand2(cand, TCL(wid + nW + step) * 16 + m, c64);

    for (int t = wid; t < nTiles; t += step) {
        // prefetch next pair's rows + pair-after-next's cands
        short8 afAn = *(const short8*)(xs + ((half < 2) ? ccA1.x : ccA1.y) * 16 + (half & 1) * 8);
        short8 afBn = *(const short8*)(xs + ((half < 2) ? ccB1.x : ccB1.y) * 16 + (half & 1) * 8);
        int2 ccA2 = ld_cand2(cand, TCL(t + 2 * step) * 16 + m, c64);
        int2 ccB2 = ld_cand2(cand, TCL(t + nW + 2 * step) * 16 + m, c64);

        // compute both tiles (independent chains -> ILP)
        float pA[4] = {0.f, 0.f, 0.f, 0.f};
        float pB[4] = {0.f, 0.f, 0.f, 0.f};
#pragma unroll
        for (int tt = 0; tt < 4; ++tt) {
            floatx4 acA = __builtin_amdgcn_mfma_f32_16x16x32_bf16(afA, bfrag[tt], zero, 0, 0, 0);
            floatx4 acB = __builtin_amdgcn_mfma_f32_16x16x32_bf16(afB, bfrag[tt], zero, 0, 0, 0);
#pragma unroll
            for (int r = 0; r < 4; ++r) {
                pA[r] = fmaf(selu_f(acA[r] + bias[tt]), w2v[tt], pA[r]);
                pB[r] = fmaf(selu_f(acB[r] + bias[tt]), w2v[tt], pB[r]);
            }
        }
#pragma unroll
        for (int off = 1; off < 16; off <<= 1) {
#pragma unroll
            for (int r = 0; r < 4; ++r) {
                pA[r] += __shfl_xor(pA[r], off, 64);
                pB[r] += __shfl_xor(pB[r], off, 64);
            }
        }
        if (m == 0) {
            if (isbf) {
                ushort4 oA;
                oA.x = f2bfbits(pA[0] + b2s);
                oA.y = f2bfbits(pA[1] + b2s);
                oA.z = f2bfbits(pA[2] + b2s);
                oA.w = f2bfbits(pA[3] + b2s);
                *(ushort4*)((unsigned short*)out + t * 16 + half * 4) = oA;
                if (t + nW < nTiles) {
                    ushort4 oB;
                    oB.x = f2bfbits(pB[0] + b2s);
                    oB.y = f2bfbits(pB[1] + b2s);
                    oB.z = f2bfbits(pB[2] + b2s);
                    oB.w = f2bfbits(pB[3] + b2s);
                    *(ushort4*)((unsigned short*)out + (t + nW) * 16 + half * 4) = oB;
                }
            } else {
                float4 oA = make_float4(pA[0] + b2s, pA[1] + b2s, pA[2] + b2s, pA[3] + b2s);
                *(float4*)((float*)out + t * 16 + half * 4) = oA;
                if (t + nW < nTiles) {
                    float4 oB = make_float4(pB[0] + b2s, pB[1] + b2s, pB[2] + b2s, pB[3] + b2s);
                    *(float4*)((float*)out + (t + nW) * 16 + half * 4) = oB;
                }
            }
        }
        afA = afAn;
        afB = afBn;
        ccA1 = ccA2;
        ccB1 = ccB2;
    }
#undef TCL
}

extern "C" void kernel_launch(void* const* d_in, const int* in_sizes, int n_in,
                              void* d_out, int out_size, void* d_ws, size_t ws_size,
                              hipStream_t stream) {
    const void* x_u = d_in[0];
    const void* x_g = d_in[1];
    const void* cand = d_in[2];
    const void* edges = d_in[3];
    const void* W1r = d_in[4];
    const void* W1o = d_in[5];
    const void* b1 = d_in[6];
    const void* W2r = d_in[7];
    const void* W2o = d_in[8];
    const void* b2 = d_in[9];
    const void* Wun = d_in[10];
    const void* bun = d_in[11];
    const void* Wfc1 = d_in[12];
    const void* bfc1 = d_in[13];
    const void* Wfc2 = d_in[14];
    const void* bfc2 = d_in[15];

    char* ws = (char*)d_ws;
    int* flags = (int*)ws;                                  // 64 B
    int* gcur = (int*)(ws + 64);                            // 782*4 -> 3200 B
    int* scur = (int*)(ws + 3264);                          // 61*4  -> 244 B
    unsigned int* glist = (unsigned int*)(ws + 4160);       // 16.01 MB
    size_t glist_bytes = (size_t)NBK * CAP * 4;             // 16010240
    char* p = ws + 4160 + glist_bytes;
    // slist (13.75 MB) overlaps the post-binning buffers: dead after k_bin2.
    unsigned int* slist = (unsigned int*)p;                 // 61*56320*4 = 13.74 MB
    int* dstoff = (int*)p;                                  // 400 KB
    int* ddeg = (int*)(p + 400000);                         // 400 KB
    unsigned short* hbf = (unsigned short*)(p + 800000);    // 1.6 MB
    unsigned short* xs = (unsigned short*)(p + 2400000);    // 6.4 MB

    hipMemsetAsync(gcur, 0, 3456, stream);   // zeroes gcur + scur

    k_detect<<<1, 64, 0, stream>>>((const unsigned int*)x_u,
                                   (const unsigned int*)cand,
                                   (const unsigned int*)edges, flags);
    k_bin1<<<(NE + SCHUNK - 1) / SCHUNK, 256, 0, stream>>>(edges, scur, slist, flags);
    k_bin2<<<NSUP * SCH2, 256, 0, stream>>>(scur, slist, gcur, glist);
    k_sort<<<NBK, 256, 0, stream>>>(gcur, glist, dstoff, ddeg);
    k_gather1<<<(8 * NG + 255) / 256, 256, 0, stream>>>(dstoff, ddeg, glist, x_g,
                                                        W1r, W1o, b1, hbf, flags);
    k_gather2<<<(8 * NG + 255) / 256, 256, 0, stream>>>(dstoff, ddeg, glist,
                                                        (const ushortx8*)hbf,
                                                        W2r, W2o, b2, xs, flags);
    k_unconn<<<(NU + 255) / 256, 256, 0, stream>>>(x_u, Wun, bun, xs, flags);
    k_fc<<<2048, 256, 0, stream>>>(xs, cand, Wfc1, bfc1, Wfc2, bfc2, d_out, flags);
}

// Round 14
// 279.815 us; speedup vs baseline: 1.2414x; 1.0688x over previous
//
#include <hip/hip_runtime.h>
#include <hip/hip_bf16.h>

#define NG 100000
#define NU 100000
#define NE 3200000
#define NC 2000000

// dst-bucket binning: 128 dsts per bucket
#define BSZ 128
#define NBK 782          // ceil(NG/BSZ)
#define CAP 5120         // entries per fine bucket (mean 4096, +16 sigma)

// two-level binning: 61 super-buckets of 13 fine buckets (61*13=793>=782)
#define NSUP 61
#define SFB 13
#define SSPAN (SFB * BSZ)   // 1664 dsts per super
#define SCAP 56320          // entries per super (mean 52459, +17 sigma)
#define SCHUNK 8192         // edges per binning block

typedef __attribute__((ext_vector_type(8))) short short8;
typedef __attribute__((ext_vector_type(4))) float floatx4;
typedef unsigned short ushortx8 __attribute__((ext_vector_type(8)));

// branchless SELU on the HW transcendental (6 VALU ops)
__device__ __forceinline__ float selu_f(float x) {
    const float LAM = 1.0507009873554805f;
    const float ALA = 1.7580993408473766f;  // LAM * ALPHA
    const float L2E = 1.44269504088896340736f;
    float e = __builtin_amdgcn_exp2f(fminf(x, 0.f) * L2E);
    return fmaf(LAM, fmaxf(x, 0.f), fmaf(ALA, e, -ALA));
}

__device__ __forceinline__ float bfbits2f(unsigned short u) {
    return __uint_as_float(((unsigned)u) << 16);
}

__device__ __forceinline__ unsigned short f2bfbits(float f) {
    union { __hip_bfloat16 h; unsigned short u; } cv;
    cv.h = __float2bfloat16(f);
    return cv.u;
}

__device__ __forceinline__ float ldf(const void* p, int i, int isbf) {
    return isbf ? bfbits2f(((const unsigned short*)p)[i]) : ((const float*)p)[i];
}

// ---- dtype detection ------------------------------------------------------
__global__ void k_detect(const unsigned int* __restrict__ xw,
                         const unsigned int* __restrict__ cw,
                         const unsigned int* __restrict__ ew,
                         int* __restrict__ flags) {
    if (threadIdx.x != 0 || blockIdx.x != 0) return;
    int nb = 0;
    for (int i = 0; i < 64; ++i) {
        unsigned lo = xw[i] & 0xffffu;
        unsigned e = (lo >> 7) & 0xff;
        if (e >= 112 && e <= 134) ++nb;
    }
    flags[0] = (nb >= 32) ? 1 : 0;
    int cz = 0, ez = 0;
    for (int i = 0; i < 64; ++i) {
        if (cw[2 * i + 1] == 0u) ++cz;
        if (ew[2 * i + 1] == 0u) ++ez;
    }
    flags[1] = (cz >= 48) ? 1 : 0;
    flags[2] = (ez >= 48) ? 1 : 0;
}

__device__ __forceinline__ void ld_edge(const void* edges, long long e, int e64,
                                        int& s, int& d) {
    if (e64) {
        const long long* el = (const long long*)edges;
        s = (int)el[e];
        d = (int)el[NE + e];
    } else {
        const int* ei = (const int*)edges;
        s = ei[e];
        d = ei[NE + e];
    }
}

// ---- Binning pass 1: edges -> 61 super-buckets (runs ~134 -> coalesced) ---
__global__ __launch_bounds__(256) void k_bin1(const void* __restrict__ edges,
        int* __restrict__ scur, unsigned int* __restrict__ slist,
        const int* __restrict__ flags) {
    __shared__ unsigned int ord[SCHUNK];       // 32 KB
    __shared__ unsigned char osup[SCHUNK];     // 8 KB
    __shared__ int hist[64];
    __shared__ int lstart[64];
    __shared__ int ofs[64];
    __shared__ int gbase[64];

    int tid = threadIdx.x;
    long long base = (long long)blockIdx.x * SCHUNK;
    int chunk = (int)(NE - base);
    if (chunk > SCHUNK) chunk = SCHUNK;
    int e64 = flags[2];

    if (tid < 64) hist[tid] = 0;
    __syncthreads();

    for (int i = 0; i < SCHUNK / 256; ++i) {
        int idx = i * 256 + tid;
        if (idx < chunk) {
            int s, d;
            ld_edge(edges, base + idx, e64, s, d);
            atomicAdd(&hist[d / SSPAN], 1);
        }
    }
    __syncthreads();

    if (tid == 0) {
        int run = 0;
        for (int b = 0; b < NSUP; ++b) {
            lstart[b] = run;
            run += hist[b];
        }
    }
    __syncthreads();
    if (tid < NSUP) {
        int c = hist[tid];
        int g = 0;
        if (c > 0) g = atomicAdd(&scur[tid], c);
        gbase[tid] = g;
        ofs[tid] = lstart[tid];
    }
    __syncthreads();

    for (int i = 0; i < SCHUNK / 256; ++i) {
        int idx = i * 256 + tid;
        if (idx < chunk) {
            int s, d;
            ld_edge(edges, base + idx, e64, s, d);
            int sup = d / SSPAN;
            int pos = atomicAdd(&ofs[sup], 1);
            ord[pos] = ((unsigned)s << 11) | (unsigned)(d - sup * SSPAN);
            osup[pos] = (unsigned char)sup;
        }
    }
    __syncthreads();

    for (int i = 0; i < SCHUNK / 256; ++i) {
        int idx = i * 256 + tid;
        if (idx < chunk) {
            int sup = osup[idx];
            int p = gbase[sup] + (idx - lstart[sup]);
            if (p < SCAP) slist[(long long)sup * SCAP + p] = ord[idx];
        }
    }
}

#define SCH2 ((SCAP + SCHUNK - 1) / SCHUNK)   // 7 chunks per super

// ---- Binning pass 2: super -> 13 fine buckets (runs ~630 -> coalesced) ----
__global__ __launch_bounds__(256) void k_bin2(const int* __restrict__ scur,
        const unsigned int* __restrict__ slist,
        int* __restrict__ gcur, unsigned int* __restrict__ glist) {
    __shared__ unsigned int ord[SCHUNK];       // 32 KB
    __shared__ unsigned char ofid[SCHUNK];     // 8 KB
    __shared__ int hist[16];
    __shared__ int lstart[16];
    __shared__ int ofs[16];
    __shared__ int gbase[16];

    int tid = threadIdx.x;
    int sup = blockIdx.x / SCH2;
    int ch = blockIdx.x % SCH2;
    int scnt = scur[sup];
    if (scnt > SCAP) scnt = SCAP;
    int start = ch * SCHUNK;
    int cnt = scnt - start;
    if (cnt <= 0) return;
    if (cnt > SCHUNK) cnt = SCHUNK;
    const unsigned int* sp = slist + (long long)sup * SCAP + start;

    if (tid < 16) hist[tid] = 0;
    __syncthreads();

    for (int i = 0; i < SCHUNK / 256; ++i) {
        int idx = i * 256 + tid;
        if (idx < cnt) {
            unsigned u = sp[idx];
            atomicAdd(&hist[(u & 2047) >> 7], 1);
        }
    }
    __syncthreads();

    if (tid == 0) {
        int run = 0;
        for (int b = 0; b < SFB; ++b) {
            lstart[b] = run;
            run += hist[b];
        }
    }
    __syncthreads();
    if (tid < SFB) {
        int c = hist[tid];
        int g = 0;
        int bf = sup * SFB + tid;
        if (c > 0 && bf < NBK) g = atomicAdd(&gcur[bf], c);
        gbase[tid] = g;
        ofs[tid] = lstart[tid];
    }
    __syncthreads();

    for (int i = 0; i < SCHUNK / 256; ++i) {
        int idx = i * 256 + tid;
        if (idx < cnt) {
            unsigned u = sp[idx];
            int dl = u & 2047;
            int f = dl >> 7;
            int pos = atomicAdd(&ofs[f], 1);
            ord[pos] = ((u >> 11) << 7) | (unsigned)(dl & 127);
            ofid[pos] = (unsigned char)f;
        }
    }
    __syncthreads();

    for (int i = 0; i < SCHUNK / 256; ++i) {
        int idx = i * 256 + tid;
        if (idx < cnt) {
            int f = ofid[idx];
            int bf = sup * SFB + f;
            int p = gbase[f] + (idx - lstart[f]);
            if (p < CAP) glist[(long long)bf * CAP + p] = ord[idx];
        }
    }
}

// ---- Counting-sort each bucket by dl, in place; emit per-dst CSR ----------
__global__ __launch_bounds__(256) void k_sort(const int* __restrict__ gcur,
        unsigned int* __restrict__ glist,
        int* __restrict__ dstoff, int* __restrict__ ddeg) {
    __shared__ unsigned int sorted[CAP];   // 20 KB
    __shared__ int hist[BSZ];
    __shared__ int incl[BSZ];
    __shared__ int cur[BSZ];
    int b = blockIdx.x;
    int tid = threadIdx.x;
    int cnt = gcur[b];
    if (cnt > CAP) cnt = CAP;
    unsigned int* lp = glist + (long long)b * CAP;

    if (tid < BSZ) hist[tid] = 0;
    __syncthreads();
    for (int k = tid; k < cnt; k += 256)
        atomicAdd(&hist[lp[k] & 127], 1);
    __syncthreads();
    if (tid < BSZ) incl[tid] = hist[tid];
    __syncthreads();
    for (int off = 1; off < BSZ; off <<= 1) {
        int v = (tid < BSZ && tid >= off) ? incl[tid - off] : 0;
        __syncthreads();
        if (tid < BSZ && tid >= off) incl[tid] += v;
        __syncthreads();
    }
    if (tid < BSZ) {
        int excl = incl[tid] - hist[tid];
        cur[tid] = excl;
        int d = b * BSZ + tid;
        if (d < NG) {
            dstoff[d] = b * CAP + excl;
            ddeg[d] = hist[tid];
        }
    }
    __syncthreads();
    for (int k = tid; k < cnt; k += 256) {
        unsigned u = lp[k];
        int pos = atomicAdd(&cur[u & 127], 1);
        sorted[pos] = u >> 7;
    }
    __syncthreads();
    for (int k = tid; k < cnt; k += 256) lp[k] = sorted[k];
}

// ---- Gather+Node 1 fused: 16 threads/dst, paired independent gathers;
//      after butterfly all 16 lanes hold the sums, lane q<8 -> output j=q ---
__global__ __launch_bounds__(256) void k_gather1(const int* __restrict__ dstoff,
        const int* __restrict__ ddeg, const unsigned int* __restrict__ glist,
        const void* __restrict__ xg,
        const void* __restrict__ W1r, const void* __restrict__ W1o,
        const void* __restrict__ b1, unsigned short* __restrict__ hbf,
        const int* __restrict__ flags) {
    int gid = blockIdx.x * 256 + threadIdx.x;
    int d = gid >> 4;
    if (d >= NG) return;
    int q = gid & 15;
    int isbf = flags[0];
    int start = dstoff[d];
    int deg = ddeg[d];
    float a0 = 0.f, a1 = 0.f, a2 = 0.f, a3 = 0.f;
    int k = q;
    for (; k + 16 < deg; k += 32) {   // two independent entries in flight
        int s0 = glist[start + k];
        int s1 = glist[start + k + 16];
        if (isbf) {
            ushort4 r0 = *(const ushort4*)((const unsigned short*)xg + s0 * 4);
            ushort4 r1 = *(const ushort4*)((const unsigned short*)xg + s1 * 4);
            a0 += bfbits2f(r0.x) + bfbits2f(r1.x);
            a1 += bfbits2f(r0.y) + bfbits2f(r1.y);
            a2 += bfbits2f(r0.z) + bfbits2f(r1.z);
            a3 += bfbits2f(r0.w) + bfbits2f(r1.w);
        } else {
            float4 r0 = *(const float4*)((const float*)xg + s0 * 4);
            float4 r1 = *(const float4*)((const float*)xg + s1 * 4);
            a0 += r0.x + r1.x;
            a1 += r0.y + r1.y;
            a2 += r0.z + r1.z;
            a3 += r0.w + r1.w;
        }
    }
    for (; k < deg; k += 16) {
        int s = glist[start + k];
        if (isbf) {
            ushort4 r = *(const ushort4*)((const unsigned short*)xg + s * 4);
            a0 += bfbits2f(r.x); a1 += bfbits2f(r.y);
            a2 += bfbits2f(r.z); a3 += bfbits2f(r.w);
        } else {
            float4 r = *(const float4*)((const float*)xg + s * 4);
            a0 += r.x; a1 += r.y; a2 += r.z; a3 += r.w;
        }
    }
#pragma unroll
    for (int off = 1; off < 16; off <<= 1) {
        a0 += __shfl_xor(a0, off);
        a1 += __shfl_xor(a1, off);
        a2 += __shfl_xor(a2, off);
        a3 += __shfl_xor(a3, off);
    }
    if (q < 8) {
        float a[4] = {a0, a1, a2, a3};
        float v = ldf(b1, q, isbf);
#pragma unroll
        for (int c = 0; c < 4; ++c)
            v += a[c] * ldf(W1r, c * 8 + q, isbf)
               + ldf(xg, d * 4 + c, isbf) * ldf(W1o, c * 8 + q, isbf);
        hbf[d * 8 + q] = f2bfbits(selu_f(v));
    }
}

// ---- Gather+Node 2 fused: 16 threads/dst; lane q -> output j=q ------------
__global__ __launch_bounds__(256) void k_gather2(const int* __restrict__ dstoff,
        const int* __restrict__ ddeg, const unsigned int* __restrict__ glist,
        const ushortx8* __restrict__ hbf,
        const void* __restrict__ W2r, const void* __restrict__ W2o,
        const void* __restrict__ b2, unsigned short* __restrict__ xs,
        const int* __restrict__ flags) {
    int gid = blockIdx.x * 256 + threadIdx.x;
    int d = gid >> 4;
    if (d >= NG) return;
    int q = gid & 15;
    int isbf = flags[0];
    int start = dstoff[d];
    int deg = ddeg[d];
    float a[8] = {0.f, 0.f, 0.f, 0.f, 0.f, 0.f, 0.f, 0.f};
    int k = q;
    for (; k + 16 < deg; k += 32) {   // two independent entries in flight
        int s0 = glist[start + k];
        int s1 = glist[start + k + 16];
        ushortx8 r0 = hbf[s0];
        ushortx8 r1 = hbf[s1];
#pragma unroll
        for (int c = 0; c < 8; ++c)
            a[c] += bfbits2f((unsigned short)r0[c]) + bfbits2f((unsigned short)r1[c]);
    }
    for (; k < deg; k += 16) {
        int s = glist[start + k];
        ushortx8 r = hbf[s];
#pragma unroll
        for (int c = 0; c < 8; ++c) a[c] += bfbits2f((unsigned short)r[c]);
    }
#pragma unroll
    for (int off = 1; off < 16; off <<= 1) {
#pragma unroll
        for (int c = 0; c < 8; ++c) a[c] += __shfl_xor(a[c], off);
    }
    // fused node MLP: lane q -> output j=q
    ushortx8 hr = hbf[d];
    float hv[8];
#pragma unroll
    for (int c = 0; c < 8; ++c) hv[c] = bfbits2f((unsigned short)hr[c]);
    float v = ldf(b2, q, isbf);
#pragma unroll
    for (int c = 0; c < 8; ++c)
        v += a[c] * ldf(W2r, c * 16 + q, isbf)
           + hv[c] * ldf(W2o, c * 16 + q, isbf);
    xs[d * 16 + q] = f2bfbits(selu_f(v));
}

// ---- fc_unconnected -> x_stacked[NG:NG+NU] (bf16), NO selu ----------------
__global__ __launch_bounds__(256) void k_unconn(const void* __restrict__ xu,
        const void* __restrict__ Wun, const void* __restrict__ bun,
        unsigned short* __restrict__ xs, const int* __restrict__ flags) {
    int u = blockIdx.x * 256 + threadIdx.x;
    if (u >= NU) return;
    int isbf = flags[0];
    float x[4];
#pragma unroll
    for (int k = 0; k < 4; ++k) x[k] = ldf(xu, u * 4 + k, isbf);
    ushortx8 lo, hi;
#pragma unroll
    for (int j = 0; j < 16; ++j) {
        float v = ldf(bun, j, isbf);
#pragma unroll
        for (int k = 0; k < 4; ++k)
            v += x[k] * ldf(Wun, k * 16 + j, isbf);
        unsigned short bb = f2bfbits(v);
        if (j < 8) lo[j] = bb; else hi[j - 8] = bb;
    }
    ushortx8* xp = (ushortx8*)(xs + (NG + u) * 16);
    xp[0] = lo;
    xp[1] = hi;
}

__device__ __forceinline__ int2 ld_cand2(const void* cand, int c, int c64) {
    if (c64) {
        const long long* cl = (const long long*)cand;
        return make_int2((int)cl[2 * c], (int)cl[2 * c + 1]);
    }
    return *(const int2*)((const int*)cand + 2 * c);
}

// ---- FC head: persistent waves, software-pipelined gather (R12 version) ---
__global__ __launch_bounds__(256) void k_fc(const unsigned short* __restrict__ xs,
        const void* __restrict__ cand,
        const void* __restrict__ Wfc1, const void* __restrict__ bfc1,
        const void* __restrict__ Wfc2, const void* __restrict__ bfc2,
        void* __restrict__ out, const int* __restrict__ flags) {
    int lane = threadIdx.x & 63;
    int wid = (blockIdx.x * blockDim.x + threadIdx.x) >> 6;
    int m = lane & 15;
    int half = lane >> 4;
    int isbf = flags[0], c64 = flags[1];

    short8 bfrag[4];
#pragma unroll
    for (int t = 0; t < 4; ++t) {
#pragma unroll
        for (int j = 0; j < 8; ++j)
            bfrag[t][j] = (short)f2bfbits(ldf(Wfc1, (half * 8 + j) * 64 + t * 16 + m, isbf));
    }
    float bias[4], w2v[4];
#pragma unroll
    for (int t = 0; t < 4; ++t) {
        bias[t] = ldf(bfc1, t * 16 + m, isbf);
        w2v[t] = ldf(Wfc2, t * 16 + m, isbf);
    }
    float b2s = ldf(bfc2, 0, isbf);
    floatx4 zero = {0.f, 0.f, 0.f, 0.f};

    const int nTiles = NC / 16;
    int nW = (gridDim.x * blockDim.x) >> 6;
    if (wid >= nTiles) return;

    int tn1 = wid + nW;
    int2 cc_cur = ld_cand2(cand, wid * 16 + m, c64);
    int tn1c = (tn1 < nTiles) ? tn1 : wid;
    int2 cc_nxt = ld_cand2(cand, tn1c * 16 + m, c64);
    {
        int row = (half < 2) ? cc_cur.x : cc_cur.y;
        short8 af_cur = *(const short8*)(xs + row * 16 + (half & 1) * 8);

        for (int t = wid; t < nTiles; t += nW) {
            int tnn = t + 2 * nW;
            int tnnc = (tnn < nTiles) ? tnn : t;
            int2 cc_n2 = ld_cand2(cand, tnnc * 16 + m, c64);
            int rown = (half < 2) ? cc_nxt.x : cc_nxt.y;
            short8 af_nxt = *(const short8*)(xs + rown * 16 + (half & 1) * 8);

            float part[4] = {0.f, 0.f, 0.f, 0.f};
#pragma unroll
            for (int tt = 0; tt < 4; ++tt) {
                floatx4 ac = __builtin_amdgcn_mfma_f32_16x16x32_bf16(af_cur, bfrag[tt], zero, 0, 0, 0);
#pragma unroll
                for (int r = 0; r < 4; ++r) {
                    float hvv = selu_f(ac[r] + bias[tt]);
                    part[r] = fmaf(hvv, w2v[tt], part[r]);
                }
            }
#pragma unroll
            for (int off = 1; off < 16; off <<= 1) {
#pragma unroll
                for (int r = 0; r < 4; ++r)
                    part[r] += __shfl_xor(part[r], off, 64);
            }
            if (m == 0) {
                if (isbf) {
                    ushort4 o;
                    o.x = f2bfbits(part[0] + b2s);
                    o.y = f2bfbits(part[1] + b2s);
                    o.z = f2bfbits(part[2] + b2s);
                    o.w = f2bfbits(part[3] + b2s);
                    *(ushort4*)((unsigned short*)out + t * 16 + half * 4) = o;
                } else {
                    float4 o = make_float4(part[0] + b2s, part[1] + b2s,
                                           part[2] + b2s, part[3] + b2s);
                    *(float4*)((float*)out + t * 16 + half * 4) = o;
                }
            }
            cc_nxt = cc_n2;
            af_cur = af_nxt;
        }
    }
}

extern "C" void kernel_launch(void* const* d_in, const int* in_sizes, int n_in,
                              void* d_out, int out_size, void* d_ws, size_t ws_size,
                              hipStream_t stream) {
    const void* x_u = d_in[0];
    const void* x_g = d_in[1];
    const void* cand = d_in[2];
    const void* edges = d_in[3];
    const void* W1r = d_in[4];
    const void* W1o = d_in[5];
    const void* b1 = d_in[6];
    const void* W2r = d_in[7];
    const void* W2o = d_in[8];
    const void* b2 = d_in[9];
    const void* Wun = d_in[10];
    const void* bun = d_in[11];
    const void* Wfc1 = d_in[12];
    const void* bfc1 = d_in[13];
    const void* Wfc2 = d_in[14];
    const void* bfc2 = d_in[15];

    char* ws = (char*)d_ws;
    int* flags = (int*)ws;                                  // 64 B
    int* gcur = (int*)(ws + 64);                            // 782*4 -> 3200 B
    int* scur = (int*)(ws + 3264);                          // 61*4  -> 244 B
    unsigned int* glist = (unsigned int*)(ws + 4160);       // 16.01 MB
    size_t glist_bytes = (size_t)NBK * CAP * 4;             // 16010240
    char* p = ws + 4160 + glist_bytes;
    // slist (13.75 MB) overlaps the post-binning buffers: dead after k_bin2.
    unsigned int* slist = (unsigned int*)p;                 // 61*56320*4 = 13.74 MB
    int* dstoff = (int*)p;                                  // 400 KB
    int* ddeg = (int*)(p + 400000);                         // 400 KB
    unsigned short* hbf = (unsigned short*)(p + 800000);    // 1.6 MB
    unsigned short* xs = (unsigned short*)(p + 2400000);    // 6.4 MB

    hipMemsetAsync(gcur, 0, 3456, stream);   // zeroes gcur + scur

    k_detect<<<1, 64, 0, stream>>>((const unsigned int*)x_u,
                                   (const unsigned int*)cand,
                                   (const unsigned int*)edges, flags);
    k_bin1<<<(NE + SCHUNK - 1) / SCHUNK, 256, 0, stream>>>(edges, scur, slist, flags);
    k_bin2<<<NSUP * SCH2, 256, 0, stream>>>(scur, slist, gcur, glist);
    k_sort<<<NBK, 256, 0, stream>>>(gcur, glist, dstoff, ddeg);
    k_gather1<<<(16 * NG + 255) / 256, 256, 0, stream>>>(dstoff, ddeg, glist, x_g,
                                                         W1r, W1o, b1, hbf, flags);
    k_gather2<<<(16 * NG + 255) / 256, 256, 0, stream>>>(dstoff, ddeg, glist,
                                                         (const ushortx8*)hbf,
                                                         W2r, W2o, b2, xs, flags);
    k_unconn<<<(NU + 255) / 256, 256, 0, stream>>>(x_u, Wun, bun, xs, flags);
    k_fc<<<2048, 256, 0, stream>>>(xs, cand, Wfc1, bfc1, Wfc2, bfc2, d_out, flags);
}

// Round 15
// 279.266 us; speedup vs baseline: 1.2438x; 1.0020x over previous
//
#include <hip/hip_runtime.h>
#include <hip/hip_bf16.h>

#define NG 100000
#define NU 100000
#define NE 3200000
#define NC 2000000

// dst-bucket binning: 128 dsts per bucket
#define BSZ 128
#define NBK 782          // ceil(NG/BSZ)
#define CAP 5120         // entries per fine bucket (mean 4096, +16 sigma)

// two-level binning: 61 super-buckets of 13 fine buckets (61*13=793>=782)
#define NSUP 61
#define SFB 13
#define SSPAN (SFB * BSZ)   // 1664 dsts per super
#define SCAP 56320          // entries per super (mean 52459, +17 sigma)
#define B1CH 4096           // edges per bin1 block (LDS-staged single read)
#define B2CH 4096           // entries per bin2 block

typedef __attribute__((ext_vector_type(8))) short short8;
typedef __attribute__((ext_vector_type(4))) float floatx4;
typedef unsigned short ushortx8 __attribute__((ext_vector_type(8)));

// branchless SELU on the HW transcendental (6 VALU ops)
__device__ __forceinline__ float selu_f(float x) {
    const float LAM = 1.0507009873554805f;
    const float ALA = 1.7580993408473766f;  // LAM * ALPHA
    const float L2E = 1.44269504088896340736f;
    float e = __builtin_amdgcn_exp2f(fminf(x, 0.f) * L2E);
    return fmaf(LAM, fmaxf(x, 0.f), fmaf(ALA, e, -ALA));
}

__device__ __forceinline__ float bfbits2f(unsigned short u) {
    return __uint_as_float(((unsigned)u) << 16);
}

__device__ __forceinline__ unsigned short f2bfbits(float f) {
    union { __hip_bfloat16 h; unsigned short u; } cv;
    cv.h = __float2bfloat16(f);
    return cv.u;
}

__device__ __forceinline__ float ldf(const void* p, int i, int isbf) {
    return isbf ? bfbits2f(((const unsigned short*)p)[i]) : ((const float*)p)[i];
}

// ---- dtype detection ------------------------------------------------------
__global__ void k_detect(const unsigned int* __restrict__ xw,
                         const unsigned int* __restrict__ cw,
                         const unsigned int* __restrict__ ew,
                         int* __restrict__ flags) {
    if (threadIdx.x != 0 || blockIdx.x != 0) return;
    int nb = 0;
    for (int i = 0; i < 64; ++i) {
        unsigned lo = xw[i] & 0xffffu;
        unsigned e = (lo >> 7) & 0xff;
        if (e >= 112 && e <= 134) ++nb;
    }
    flags[0] = (nb >= 32) ? 1 : 0;
    int cz = 0, ez = 0;
    for (int i = 0; i < 64; ++i) {
        if (cw[2 * i + 1] == 0u) ++cz;
        if (ew[2 * i + 1] == 0u) ++ez;
    }
    flags[1] = (cz >= 48) ? 1 : 0;
    flags[2] = (ez >= 48) ? 1 : 0;
}

__device__ __forceinline__ void ld_edge(const void* edges, long long e, int e64,
                                        int& s, int& d) {
    if (e64) {
        const long long* el = (const long long*)edges;
        s = (int)el[e];
        d = (int)el[NE + e];
    } else {
        const int* ei = (const int*)edges;
        s = ei[e];
        d = ei[NE + e];
    }
}

// ---- Binning pass 1: edges -> 61 super-buckets. SINGLE global read:
//      entries staged in LDS during the histogram pass. Runs ~67 entries
//      (268 B) at 61 buckets -> still fully coalesced writes. --------------
__global__ __launch_bounds__(256) void k_bin1(const void* __restrict__ edges,
        int* __restrict__ scur, unsigned int* __restrict__ slist,
        const int* __restrict__ flags) {
    __shared__ unsigned int tmp[B1CH];         // 16 KB  (s<<11)|dlocal
    __shared__ unsigned char tsup[B1CH];       // 4 KB
    __shared__ unsigned int ord[B1CH];         // 16 KB
    __shared__ unsigned char osup[B1CH];       // 4 KB
    __shared__ int hist[64];
    __shared__ int lstart[64];
    __shared__ int ofs[64];
    __shared__ int gbase[64];                  // ~41 KB -> 3 blocks/CU

    int tid = threadIdx.x;
    long long base = (long long)blockIdx.x * B1CH;
    int chunk = (int)(NE - base);
    if (chunk > B1CH) chunk = B1CH;
    int e64 = flags[2];

    if (tid < 64) hist[tid] = 0;
    __syncthreads();

    // phase A: single global read -> LDS stage + histogram
    for (int i = 0; i < B1CH / 256; ++i) {
        int idx = i * 256 + tid;
        if (idx < chunk) {
            int s, d;
            ld_edge(edges, base + idx, e64, s, d);
            int sup = d / SSPAN;
            tmp[idx] = ((unsigned)s << 11) | (unsigned)(d - sup * SSPAN);
            tsup[idx] = (unsigned char)sup;
            atomicAdd(&hist[sup], 1);
        }
    }
    __syncthreads();

    // phase B: serial scan (61) + global reservation
    if (tid == 0) {
        int run = 0;
        for (int b = 0; b < NSUP; ++b) {
            lstart[b] = run;
            run += hist[b];
        }
    }
    __syncthreads();
    if (tid < NSUP) {
        int c = hist[tid];
        int g = 0;
        if (c > 0) g = atomicAdd(&scur[tid], c);
        gbase[tid] = g;
        ofs[tid] = lstart[tid];
    }
    __syncthreads();

    // phase C: reorder within LDS
    for (int i = 0; i < B1CH / 256; ++i) {
        int idx = i * 256 + tid;
        if (idx < chunk) {
            int sup = tsup[idx];
            int pos = atomicAdd(&ofs[sup], 1);
            ord[pos] = tmp[idx];
            osup[pos] = (unsigned char)sup;
        }
    }
    __syncthreads();

    // phase D: coalesced write-out
    for (int i = 0; i < B1CH / 256; ++i) {
        int idx = i * 256 + tid;
        if (idx < chunk) {
            int sup = osup[idx];
            int p = gbase[sup] + (idx - lstart[sup]);
            if (p < SCAP) slist[(long long)sup * SCAP + p] = ord[idx];
        }
    }
}

#define SCH2 ((SCAP + B2CH - 1) / B2CH)   // 14 chunks per super

// ---- Binning pass 2: super -> 13 fine buckets. SINGLE slist read. --------
__global__ __launch_bounds__(256) void k_bin2(const int* __restrict__ scur,
        const unsigned int* __restrict__ slist,
        int* __restrict__ gcur, unsigned int* __restrict__ glist) {
    __shared__ unsigned int tmp[B2CH];         // 16 KB
    __shared__ unsigned int ord[B2CH];         // 16 KB
    __shared__ unsigned char ofid[B2CH];       // 4 KB
    __shared__ int hist[16];
    __shared__ int lstart[16];
    __shared__ int ofs[16];
    __shared__ int gbase[16];                  // ~36.5 KB -> 4 blocks/CU

    int tid = threadIdx.x;
    int sup = blockIdx.x / SCH2;
    int ch = blockIdx.x % SCH2;
    int scnt = scur[sup];
    if (scnt > SCAP) scnt = SCAP;
    int start = ch * B2CH;
    int cnt = scnt - start;
    if (cnt <= 0) return;
    if (cnt > B2CH) cnt = B2CH;
    const unsigned int* sp = slist + (long long)sup * SCAP + start;

    if (tid < 16) hist[tid] = 0;
    __syncthreads();

    // phase A: single global read -> LDS stage + histogram
    for (int i = 0; i < B2CH / 256; ++i) {
        int idx = i * 256 + tid;
        if (idx < cnt) {
            unsigned u = sp[idx];
            tmp[idx] = u;
            atomicAdd(&hist[(u & 2047) >> 7], 1);
        }
    }
    __syncthreads();

    if (tid == 0) {
        int run = 0;
        for (int b = 0; b < SFB; ++b) {
            lstart[b] = run;
            run += hist[b];
        }
    }
    __syncthreads();
    if (tid < SFB) {
        int c = hist[tid];
        int g = 0;
        int bf = sup * SFB + tid;
        if (c > 0 && bf < NBK) g = atomicAdd(&gcur[bf], c);
        gbase[tid] = g;
        ofs[tid] = lstart[tid];
    }
    __syncthreads();

    // phase C: reorder within LDS (convert to (s<<7)|dl127)
    for (int i = 0; i < B2CH / 256; ++i) {
        int idx = i * 256 + tid;
        if (idx < cnt) {
            unsigned u = tmp[idx];
            int dl = u & 2047;
            int f = dl >> 7;
            int pos = atomicAdd(&ofs[f], 1);
            ord[pos] = ((u >> 11) << 7) | (unsigned)(dl & 127);
            ofid[pos] = (unsigned char)f;
        }
    }
    __syncthreads();

    // phase D: coalesced write-out (runs ~315 entries)
    for (int i = 0; i < B2CH / 256; ++i) {
        int idx = i * 256 + tid;
        if (idx < cnt) {
            int f = ofid[idx];
            int bf = sup * SFB + f;
            int p = gbase[f] + (idx - lstart[f]);
            if (p < CAP) glist[(long long)bf * CAP + p] = ord[idx];
        }
    }
}

// ---- Counting-sort each bucket by dl. SINGLE glist read (LDS-staged),
//      in-place write-back; emits per-dst CSR. -----------------------------
__global__ __launch_bounds__(256) void k_sort(const int* __restrict__ gcur,
        unsigned int* __restrict__ glist,
        int* __restrict__ dstoff, int* __restrict__ ddeg) {
    __shared__ unsigned int tmp[CAP];      // 20 KB
    __shared__ unsigned int sorted[CAP];   // 20 KB
    __shared__ int hist[BSZ];
    __shared__ int incl[BSZ];
    __shared__ int cur[BSZ];               // ~41.5 KB -> 3 blocks/CU
    int b = blockIdx.x;
    int tid = threadIdx.x;
    int cnt = gcur[b];
    if (cnt > CAP) cnt = CAP;
    unsigned int* lp = glist + (long long)b * CAP;

    if (tid < BSZ) hist[tid] = 0;
    __syncthreads();
    // single global read -> LDS + histogram
    for (int k = tid; k < cnt; k += 256) {
        unsigned u = lp[k];
        tmp[k] = u;
        atomicAdd(&hist[u & 127], 1);
    }
    __syncthreads();
    if (tid < BSZ) incl[tid] = hist[tid];
    __syncthreads();
    for (int off = 1; off < BSZ; off <<= 1) {
        int v = (tid < BSZ && tid >= off) ? incl[tid - off] : 0;
        __syncthreads();
        if (tid < BSZ && tid >= off) incl[tid] += v;
        __syncthreads();
    }
    if (tid < BSZ) {
        int excl = incl[tid] - hist[tid];
        cur[tid] = excl;
        int d = b * BSZ + tid;
        if (d < NG) {
            dstoff[d] = b * CAP + excl;
            ddeg[d] = hist[tid];
        }
    }
    __syncthreads();
    for (int k = tid; k < cnt; k += 256) {
        unsigned u = tmp[k];
        int pos = atomicAdd(&cur[u & 127], 1);
        sorted[pos] = u >> 7;
    }
    __syncthreads();
    for (int k = tid; k < cnt; k += 256) lp[k] = sorted[k];
}

// ---- Gather+Node 1 fused: 16 threads/dst, paired independent gathers ------
__global__ __launch_bounds__(256) void k_gather1(const int* __restrict__ dstoff,
        const int* __restrict__ ddeg, const unsigned int* __restrict__ glist,
        const void* __restrict__ xg,
        const void* __restrict__ W1r, const void* __restrict__ W1o,
        const void* __restrict__ b1, unsigned short* __restrict__ hbf,
        const int* __restrict__ flags) {
    int gid = blockIdx.x * 256 + threadIdx.x;
    int d = gid >> 4;
    if (d >= NG) return;
    int q = gid & 15;
    int isbf = flags[0];
    int start = dstoff[d];
    int deg = ddeg[d];
    float a0 = 0.f, a1 = 0.f, a2 = 0.f, a3 = 0.f;
    int k = q;
    for (; k + 16 < deg; k += 32) {
        int s0 = glist[start + k];
        int s1 = glist[start + k + 16];
        if (isbf) {
            ushort4 r0 = *(const ushort4*)((const unsigned short*)xg + s0 * 4);
            ushort4 r1 = *(const ushort4*)((const unsigned short*)xg + s1 * 4);
            a0 += bfbits2f(r0.x) + bfbits2f(r1.x);
            a1 += bfbits2f(r0.y) + bfbits2f(r1.y);
            a2 += bfbits2f(r0.z) + bfbits2f(r1.z);
            a3 += bfbits2f(r0.w) + bfbits2f(r1.w);
        } else {
            float4 r0 = *(const float4*)((const float*)xg + s0 * 4);
            float4 r1 = *(const float4*)((const float*)xg + s1 * 4);
            a0 += r0.x + r1.x;
            a1 += r0.y + r1.y;
            a2 += r0.z + r1.z;
            a3 += r0.w + r1.w;
        }
    }
    for (; k < deg; k += 16) {
        int s = glist[start + k];
        if (isbf) {
            ushort4 r = *(const ushort4*)((const unsigned short*)xg + s * 4);
            a0 += bfbits2f(r.x); a1 += bfbits2f(r.y);
            a2 += bfbits2f(r.z); a3 += bfbits2f(r.w);
        } else {
            float4 r = *(const float4*)((const float*)xg + s * 4);
            a0 += r.x; a1 += r.y; a2 += r.z; a3 += r.w;
        }
    }
#pragma unroll
    for (int off = 1; off < 16; off <<= 1) {
        a0 += __shfl_xor(a0, off);
        a1 += __shfl_xor(a1, off);
        a2 += __shfl_xor(a2, off);
        a3 += __shfl_xor(a3, off);
    }
    if (q < 8) {
        float a[4] = {a0, a1, a2, a3};
        float v = ldf(b1, q, isbf);
#pragma unroll
        for (int c = 0; c < 4; ++c)
            v += a[c] * ldf(W1r, c * 8 + q, isbf)
               + ldf(xg, d * 4 + c, isbf) * ldf(W1o, c * 8 + q, isbf);
        hbf[d * 8 + q] = f2bfbits(selu_f(v));
    }
}

// ---- Gather+Node 2 fused: 16 threads/dst; lane q -> output j=q ------------
__global__ __launch_bounds__(256) void k_gather2(const int* __restrict__ dstoff,
        const int* __restrict__ ddeg, const unsigned int* __restrict__ glist,
        const ushortx8* __restrict__ hbf,
        const void* __restrict__ W2r, const void* __restrict__ W2o,
        const void* __restrict__ b2, unsigned short* __restrict__ xs,
        const int* __restrict__ flags) {
    int gid = blockIdx.x * 256 + threadIdx.x;
    int d = gid >> 4;
    if (d >= NG) return;
    int q = gid & 15;
    int isbf = flags[0];
    int start = dstoff[d];
    int deg = ddeg[d];
    float a[8] = {0.f, 0.f, 0.f, 0.f, 0.f, 0.f, 0.f, 0.f};
    int k = q;
    for (; k + 16 < deg; k += 32) {
        int s0 = glist[start + k];
        int s1 = glist[start + k + 16];
        ushortx8 r0 = hbf[s0];
        ushortx8 r1 = hbf[s1];
#pragma unroll
        for (int c = 0; c < 8; ++c)
            a[c] += bfbits2f((unsigned short)r0[c]) + bfbits2f((unsigned short)r1[c]);
    }
    for (; k < deg; k += 16) {
        int s = glist[start + k];
        ushortx8 r = hbf[s];
#pragma unroll
        for (int c = 0; c < 8; ++c) a[c] += bfbits2f((unsigned short)r[c]);
    }
#pragma unroll
    for (int off = 1; off < 16; off <<= 1) {
#pragma unroll
        for (int c = 0; c < 8; ++c) a[c] += __shfl_xor(a[c], off);
    }
    ushortx8 hr = hbf[d];
    float hv[8];
#pragma unroll
    for (int c = 0; c < 8; ++c) hv[c] = bfbits2f((unsigned short)hr[c]);
    float v = ldf(b2, q, isbf);
#pragma unroll
    for (int c = 0; c < 8; ++c)
        v += a[c] * ldf(W2r, c * 16 + q, isbf)
           + hv[c] * ldf(W2o, c * 16 + q, isbf);
    xs[d * 16 + q] = f2bfbits(selu_f(v));
}

// ---- fc_unconnected -> x_stacked[NG:NG+NU] (bf16), NO selu ----------------
__global__ __launch_bounds__(256) void k_unconn(const void* __restrict__ xu,
        const void* __restrict__ Wun, const void* __restrict__ bun,
        unsigned short* __restrict__ xs, const int* __restrict__ flags) {
    int u = blockIdx.x * 256 + threadIdx.x;
    if (u >= NU) return;
    int isbf = flags[0];
    float x[4];
#pragma unroll
    for (int k = 0; k < 4; ++k) x[k] = ldf(xu, u * 4 + k, isbf);
    ushortx8 lo, hi;
#pragma unroll
    for (int j = 0; j < 16; ++j) {
        float v = ldf(bun, j, isbf);
#pragma unroll
        for (int k = 0; k < 4; ++k)
            v += x[k] * ldf(Wun, k * 16 + j, isbf);
        unsigned short bb = f2bfbits(v);
        if (j < 8) lo[j] = bb; else hi[j - 8] = bb;
    }
    ushortx8* xp = (ushortx8*)(xs + (NG + u) * 16);
    xp[0] = lo;
    xp[1] = hi;
}

__device__ __forceinline__ int2 ld_cand2(const void* cand, int c, int c64) {
    if (c64) {
        const long long* cl = (const long long*)cand;
        return make_int2((int)cl[2 * c], (int)cl[2 * c + 1]);
    }
    return *(const int2*)((const int*)cand + 2 * c);
}

// ---- FC head: persistent waves, software-pipelined gather (R12 version) ---
__global__ __launch_bounds__(256) void k_fc(const unsigned short* __restrict__ xs,
        const void* __restrict__ cand,
        const void* __restrict__ Wfc1, const void* __restrict__ bfc1,
        const void* __restrict__ Wfc2, const void* __restrict__ bfc2,
        void* __restrict__ out, const int* __restrict__ flags) {
    int lane = threadIdx.x & 63;
    int wid = (blockIdx.x * blockDim.x + threadIdx.x) >> 6;
    int m = lane & 15;
    int half = lane >> 4;
    int isbf = flags[0], c64 = flags[1];

    short8 bfrag[4];
#pragma unroll
    for (int t = 0; t < 4; ++t) {
#pragma unroll
        for (int j = 0; j < 8; ++j)
            bfrag[t][j] = (short)f2bfbits(ldf(Wfc1, (half * 8 + j) * 64 + t * 16 + m, isbf));
    }
    float bias[4], w2v[4];
#pragma unroll
    for (int t = 0; t < 4; ++t) {
        bias[t] = ldf(bfc1, t * 16 + m, isbf);
        w2v[t] = ldf(Wfc2, t * 16 + m, isbf);
    }
    float b2s = ldf(bfc2, 0, isbf);
    floatx4 zero = {0.f, 0.f, 0.f, 0.f};

    const int nTiles = NC / 16;
    int nW = (gridDim.x * blockDim.x) >> 6;
    if (wid >= nTiles) return;

    int tn1 = wid + nW;
    int2 cc_cur = ld_cand2(cand, wid * 16 + m, c64);
    int tn1c = (tn1 < nTiles) ? tn1 : wid;
    int2 cc_nxt = ld_cand2(cand, tn1c * 16 + m, c64);
    {
        int row = (half < 2) ? cc_cur.x : cc_cur.y;
        short8 af_cur = *(const short8*)(xs + row * 16 + (half & 1) * 8);

        for (int t = wid; t < nTiles; t += nW) {
            int tnn = t + 2 * nW;
            int tnnc = (tnn < nTiles) ? tnn : t;
            int2 cc_n2 = ld_cand2(cand, tnnc * 16 + m, c64);
            int rown = (half < 2) ? cc_nxt.x : cc_nxt.y;
            short8 af_nxt = *(const short8*)(xs + rown * 16 + (half & 1) * 8);

            float part[4] = {0.f, 0.f, 0.f, 0.f};
#pragma unroll
            for (int tt = 0; tt < 4; ++tt) {
                floatx4 ac = __builtin_amdgcn_mfma_f32_16x16x32_bf16(af_cur, bfrag[tt], zero, 0, 0, 0);
#pragma unroll
                for (int r = 0; r < 4; ++r) {
                    float hvv = selu_f(ac[r] + bias[tt]);
                    part[r] = fmaf(hvv, w2v[tt], part[r]);
                }
            }
#pragma unroll
            for (int off = 1; off < 16; off <<= 1) {
#pragma unroll
                for (int r = 0; r < 4; ++r)
                    part[r] += __shfl_xor(part[r], off, 64);
            }
            if (m == 0) {
                if (isbf) {
                    ushort4 o;
                    o.x = f2bfbits(part[0] + b2s);
                    o.y = f2bfbits(part[1] + b2s);
                    o.z = f2bfbits(part[2] + b2s);
                    o.w = f2bfbits(part[3] + b2s);
                    *(ushort4*)((unsigned short*)out + t * 16 + half * 4) = o;
                } else {
                    float4 o = make_float4(part[0] + b2s, part[1] + b2s,
                                           part[2] + b2s, part[3] + b2s);
                    *(float4*)((float*)out + t * 16 + half * 4) = o;
                }
            }
            cc_nxt = cc_n2;
            af_cur = af_nxt;
        }
    }
}

extern "C" void kernel_launch(void* const* d_in, const int* in_sizes, int n_in,
                              void* d_out, int out_size, void* d_ws, size_t ws_size,
                              hipStream_t stream) {
    const void* x_u = d_in[0];
    const void* x_g = d_in[1];
    const void* cand = d_in[2];
    const void* edges = d_in[3];
    const void* W1r = d_in[4];
    const void* W1o = d_in[5];
    const void* b1 = d_in[6];
    const void* W2r = d_in[7];
    const void* W2o = d_in[8];
    const void* b2 = d_in[9];
    const void* Wun = d_in[10];
    const void* bun = d_in[11];
    const void* Wfc1 = d_in[12];
    const void* bfc1 = d_in[13];
    const void* Wfc2 = d_in[14];
    const void* bfc2 = d_in[15];

    char* ws = (char*)d_ws;
    int* flags = (int*)ws;                                  // 64 B
    int* gcur = (int*)(ws + 64);                            // 782*4 -> 3200 B
    int* scur = (int*)(ws + 3264);                          // 61*4  -> 244 B
    unsigned int* glist = (unsigned int*)(ws + 4160);       // 16.01 MB
    size_t glist_bytes = (size_t)NBK * CAP * 4;             // 16010240
    char* p = ws + 4160 + glist_bytes;
    // slist (13.75 MB) overlaps the post-binning buffers: dead after k_bin2.
    unsigned int* slist = (unsigned int*)p;                 // 61*56320*4 = 13.74 MB
    int* dstoff = (int*)p;                                  // 400 KB
    int* ddeg = (int*)(p + 400000);                         // 400 KB
    unsigned short* hbf = (unsigned short*)(p + 800000);    // 1.6 MB
    unsigned short* xs = (unsigned short*)(p + 2400000);    // 6.4 MB

    hipMemsetAsync(gcur, 0, 3456, stream);   // zeroes gcur + scur

    k_detect<<<1, 64, 0, stream>>>((const unsigned int*)x_u,
                                   (const unsigned int*)cand,
                                   (const unsigned int*)edges, flags);
    k_bin1<<<(NE + B1CH - 1) / B1CH, 256, 0, stream>>>(edges, scur, slist, flags);
    k_bin2<<<NSUP * SCH2, 256, 0, stream>>>(scur, slist, gcur, glist);
    k_sort<<<NBK, 256, 0, stream>>>(gcur, glist, dstoff, ddeg);
    k_gather1<<<(16 * NG + 255) / 256, 256, 0, stream>>>(dstoff, ddeg, glist, x_g,
                                                         W1r, W1o, b1, hbf, flags);
    k_gather2<<<(16 * NG + 255) / 256, 256, 0, stream>>>(dstoff, ddeg, glist,
                                                         (const ushortx8*)hbf,
                                                         W2r, W2o, b2, xs, flags);
    k_unconn<<<(NU + 255) / 256, 256, 0, stream>>>(x_u, Wun, bun, xs, flags);
    k_fc<<<2048, 256, 0, stream>>>(xs, cand, Wfc1, bfc1, Wfc2, bfc2, d_out, flags);
}